// Round 2
// baseline (218.298 us; speedup 1.0000x reference)
//
#include <hip/hip_runtime.h>

typedef __bf16 bf16;
typedef __attribute__((ext_vector_type(8))) __bf16 bf16x8;
typedef __attribute__((ext_vector_type(4))) float f32x4;
typedef __attribute__((ext_vector_type(16))) float f32x16;
typedef unsigned int u32;

#define MFMA16(a, b, c) __builtin_amdgcn_mfma_f32_16x16x32_bf16((a), (b), (c), 0, 0, 0)
#define MFMA32(a, b, c) __builtin_amdgcn_mfma_f32_32x32x16_bf16((a), (b), (c), 0, 0, 0)

// Problem constants
#define BB 2
#define SS 2048
#define EE 1024
#define HH 16
#define DD 64
#define MM (BB * SS)  // 4096

__device__ inline f32x4 zero4() {
    f32x4 z; z.x = 0.f; z.y = 0.f; z.z = 0.f; z.w = 0.f; return z;
}

// async global->LDS DMA, 16B per lane.  LDS dest = wave-uniform base + lane*16.
__device__ __forceinline__ void gload16(const bf16* g, bf16* l) {
    __builtin_amdgcn_global_load_lds(
        (const __attribute__((address_space(1))) u32*)(const void*)g,
        (__attribute__((address_space(3))) u32*)(void*)l,
        16, 0, 0);
}

__device__ __forceinline__ u32 pkbf(float a, float b) {
    union { __bf16 h; unsigned short s; } ua, ub;
    ua.h = (__bf16)a; ub.h = (__bf16)b;
    return (u32)ua.s | ((u32)ub.s << 16);
}

// ---------------------------------------------------------------------------
// Kernel 1: fused prep.
// ---------------------------------------------------------------------------
__global__ __launch_bounds__(256) void prep_kernel(
    const float* __restrict__ query, bf16* __restrict__ qc,
    const float* __restrict__ s0, const float* __restrict__ s1,
    const float* __restrict__ s2, const float* __restrict__ s3,
    bf16* __restrict__ d0, bf16* __restrict__ d1,
    bf16* __restrict__ d2, bf16* __restrict__ d3,
    const float* __restrict__ xi, const float* __restrict__ w1,
    const float* __restrict__ b1, const float* __restrict__ lng,
    const float* __restrict__ lnb, const float* __restrict__ w2,
    const float* __restrict__ b2, const float* __restrict__ gate,
    float* __restrict__ adapt) {
    __shared__ bf16 tile[64 * 72];
    const int bid = blockIdx.x;
    const int t = threadIdx.x;

    if (bid < 2048) {
        const int i = (bid * 256 + t) * 8;
        float4 a = *(const float4*)(query + i);
        float4 b = *(const float4*)(query + i + 4);
        bf16 tmp[8];
        tmp[0] = (bf16)a.x; tmp[1] = (bf16)a.y; tmp[2] = (bf16)a.z; tmp[3] = (bf16)a.w;
        tmp[4] = (bf16)b.x; tmp[5] = (bf16)b.y; tmp[6] = (bf16)b.z; tmp[7] = (bf16)b.w;
        *(uint4*)(qc + i) = *(uint4*)tmp;
    } else if (bid < 3072) {
        const int m = (bid - 2048) >> 8;
        const int idx0 = (bid - 2048) & 255;
        const float* W = (m == 0) ? s0 : (m == 1) ? s1 : (m == 2) ? s2 : s3;
        bf16* Wt = (m == 0) ? d0 : (m == 1) ? d1 : (m == 2) ? d2 : d3;
        const int k0 = (idx0 >> 4) * 64, n0 = (idx0 & 15) * 64;
#pragma unroll
        for (int i = 0; i < 2; ++i) {
            int idx = i * 256 + t;
            int r = idx >> 3, c = (idx & 7) * 8;
            float4 a = *(const float4*)(W + (k0 + r) * EE + n0 + c);
            float4 b = *(const float4*)(W + (k0 + r) * EE + n0 + c + 4);
            bf16 tmp[8];
            tmp[0] = (bf16)a.x; tmp[1] = (bf16)a.y; tmp[2] = (bf16)a.z; tmp[3] = (bf16)a.w;
            tmp[4] = (bf16)b.x; tmp[5] = (bf16)b.y; tmp[6] = (bf16)b.z; tmp[7] = (bf16)b.w;
            *(uint4*)(tile + r * 72 + c) = *(uint4*)tmp;
        }
        __syncthreads();
#pragma unroll
        for (int i = 0; i < 2; ++i) {
            int idx = i * 256 + t;
            int n = idx >> 3, kc = (idx & 7) * 8;
            bf16 tmp[8];
#pragma unroll
            for (int j = 0; j < 8; ++j) tmp[j] = tile[(kc + j) * 72 + n];
            *(uint4*)(Wt + (n0 + n) * EE + k0 + kc) = *(uint4*)tmp;
        }
    } else {
        const int b = bid - 3072;
        float* xs = (float*)tile;
        if (t < 64) {
            const float xiv = xi[b];
            float xv = 0.f;
            if (t < 32) xv = xiv * w1[t] + b1[t];
            float sm = xv;
            for (int off = 1; off < 32; off <<= 1) sm += __shfl_xor(sm, off);
            const float mu = sm * (1.f / 32.f);
            float dv = (t < 32) ? (xv - mu) : 0.f;
            float s2 = dv * dv;
            for (int off = 1; off < 32; off <<= 1) s2 += __shfl_xor(s2, off);
            const float var = s2 * (1.f / 32.f);
            if (t < 32) {
                float xn = (xv - mu) * rsqrtf(var + 1e-5f) * lng[t] + lnb[t];
                float ge = 0.5f * xn * (1.f + erff(xn * 0.70710678118654752f));
                xs[t] = ge;
            }
        }
        __syncthreads();
        if (t < 64) {
            float acc = b2[t];
            for (int j = 0; j < 32; ++j) acc += xs[j] * w2[j * DD + t];
            for (int h = 0; h < HH; ++h) {
                float sg = 1.f / (1.f + __expf(-gate[h]));
                adapt[(b * HH + h) * DD + t] = 1.f + sg * acc;
            }
        }
    }
}

// ---------------------------------------------------------------------------
// Kernel 2: QKV GEMM — 128x128 tile, BK=32, dbuf DMA, one barrier/iter.
// q-scale folds 0.125*log2(e) so attention uses bare v_exp_f32 (exp2).
// ---------------------------------------------------------------------------
__global__ __launch_bounds__(256, 3) void gemm_qkv(
    const bf16* __restrict__ Aq, const bf16* __restrict__ Bqk,
    const bf16* __restrict__ Av,
    const float* __restrict__ bias, const float* __restrict__ bias2,
    const float* __restrict__ bias3, const float* __restrict__ adapt,
    bf16* __restrict__ outqk, bf16* __restrict__ outvt) {
    __shared__ bf16 As[2 * 128 * 32];
    __shared__ bf16 Bs[2 * 128 * 32];

    const int t = threadIdx.x;
    const int w = t >> 6, lane = t & 63;
    const int mrow = lane & 15, quad = lane >> 4;
    const int wm = (w & 1) * 64, wn = (w >> 1) * 64;

    int md, bx, by;
    const bf16 *Ap, *Bp;
    int bid = blockIdx.x;
    if (bid < 512) { md = 5; bx = bid & 31; by = bid >> 5; Ap = Aq; Bp = Bqk; }
    else { md = 4; bid -= 512; bx = bid & 7; by = bid >> 3; Ap = Av; Bp = Aq; }
    const int m0 = bx * 128, n0 = by * 128;

    f32x4 acc[4][4];
#pragma unroll
    for (int i = 0; i < 4; ++i)
#pragma unroll
        for (int j = 0; j < 4; ++j) acc[i][j] = zero4();

    const int dr = lane >> 2;
    const int dcg = ((lane & 3) ^ (dr & 3)) * 8;
    const bf16* Ag = Ap + (size_t)(m0 + w * 16 + dr) * EE + dcg;
    const bf16* Bg = Bp + (size_t)(n0 + w * 16 + dr) * EE + dcg;
    bf16* Al = As + (w * 16) * 32;
    bf16* Bl = Bs + (w * 16) * 32;

    gload16(Ag, Al);
    gload16(Ag + 64 * EE, Al + 64 * 32);
    gload16(Bg, Bl);
    gload16(Bg + 64 * EE, Bl + 64 * 32);

    for (int kt = 0; kt < 32; ++kt) {
        __syncthreads();
        if (kt < 31) {
            const int kn = (kt + 1) * 32;
            const int nb = (kt + 1) & 1;
            gload16(Ag + kn, Al + nb * 4096);
            gload16(Ag + 64 * EE + kn, Al + nb * 4096 + 64 * 32);
            gload16(Bg + kn, Bl + nb * 4096);
            gload16(Bg + 64 * EE + kn, Bl + nb * 4096 + 64 * 32);
        }
        const bf16* Ab = As + (kt & 1) * 4096;
        const bf16* Bb = Bs + (kt & 1) * 4096;
        const int sw = (quad ^ (mrow & 3)) * 8;
        bf16x8 af[4], bfr[4];
#pragma unroll
        for (int i = 0; i < 4; ++i)
            af[i] = *(const bf16x8*)(Ab + (wm + i * 16 + mrow) * 32 + sw);
#pragma unroll
        for (int j = 0; j < 4; ++j)
            bfr[j] = *(const bf16x8*)(Bb + (wn + j * 16 + mrow) * 32 + sw);
#pragma unroll
        for (int i = 0; i < 4; ++i)
#pragma unroll
            for (int j = 0; j < 4; ++j)
                acc[i][j] = MFMA16(af[i], bfr[j], acc[i][j]);
    }

#pragma unroll
    for (int i = 0; i < 4; ++i) {
#pragma unroll
        for (int j = 0; j < 4; ++j) {
            const int col = n0 + wn + j * 16 + mrow;
#pragma unroll
            for (int r = 0; r < 4; ++r) {
                const int row = m0 + wm + i * 16 + quad * 4 + r;
                float v = acc[i][j][r];
                if (md == 4) {
                    v += bias3[row];
                    const int h = row >> 6, d = row & 63;
                    const int b = col >> 11, s = col & (SS - 1);
                    outvt[(((b * HH + h) * DD + d) * SS) + s] = (bf16)v;
                } else {
                    const int m2 = col >> 10;
                    const int cl = col & 1023;
                    const int h = cl >> 6, d = cl & 63;
                    const int b = row >> 11, s = row & (SS - 1);
                    v += (m2 ? bias2[cl] : bias[cl]);
                    v *= adapt[(b * HH + h) * DD + d];
                    // q: 1/sqrt(64) * log2(e) folded (attn uses exp2)
                    if (!m2) v *= 0.18033688011113811f;
                    outqk[(size_t)m2 * MM * EE + ((b * HH + h) * SS + s) * DD + d] = (bf16)v;
                }
            }
        }
    }
}

// ---------------------------------------------------------------------------
// Kernel 3: final GEMM.
// ---------------------------------------------------------------------------
__global__ __launch_bounds__(256, 3) void gemm_o(
    const bf16* __restrict__ A, const bf16* __restrict__ Bt,
    const float* __restrict__ bias, float* __restrict__ outf) {
    __shared__ bf16 As[2 * 128 * 64];
    __shared__ bf16 Bs[2 * 64 * 64];

    const int t = threadIdx.x;
    const int w = t >> 6, lane = t & 63;
    const int mrow = lane & 15, quad = lane >> 4;
    const int m0 = blockIdx.x * 128, n0 = blockIdx.y * 64;

    f32x4 acc[2][4];
#pragma unroll
    for (int i = 0; i < 2; ++i)
#pragma unroll
        for (int j = 0; j < 4; ++j) acc[i][j] = zero4();

    const int grow = lane >> 3;
    const int gsw = ((lane & 7) ^ grow) * 8;
    const bf16* Ag = A + (size_t)(m0 + w * 32 + grow) * EE + gsw;
    const bf16* Bg = Bt + (size_t)(n0 + w * 16 + grow) * EE + gsw;
    bf16* Al = As + (w * 32) * 64;
    bf16* Bl = Bs + (w * 16) * 64;

#pragma unroll
    for (int i = 0; i < 4; ++i) gload16(Ag + i * 8 * EE, Al + i * 8 * 64);
#pragma unroll
    for (int i = 0; i < 2; ++i) gload16(Bg + i * 8 * EE, Bl + i * 8 * 64);

    for (int kt = 0; kt < 16; ++kt) {
        __syncthreads();
        if (kt < 15) {
            const int kn = (kt + 1) * 64;
            const int nb = (kt + 1) & 1;
#pragma unroll
            for (int i = 0; i < 4; ++i)
                gload16(Ag + i * 8 * EE + kn, Al + nb * 8192 + i * 8 * 64);
#pragma unroll
            for (int i = 0; i < 2; ++i)
                gload16(Bg + i * 8 * EE + kn, Bl + nb * 4096 + i * 8 * 64);
        }
        const bf16* Ab = As + (kt & 1) * 8192;
        const bf16* Bb = Bs + (kt & 1) * 4096;
#pragma unroll
        for (int ks = 0; ks < 2; ++ks) {
            const int cg = ks * 4 + quad;
            const int sw = (cg ^ (mrow & 7)) * 8;
            bf16x8 af[2], bfr[4];
#pragma unroll
            for (int mi = 0; mi < 2; ++mi)
                af[mi] = *(const bf16x8*)(Ab + (w * 32 + mi * 16 + mrow) * 64 + sw);
#pragma unroll
            for (int nj = 0; nj < 4; ++nj)
                bfr[nj] = *(const bf16x8*)(Bb + (nj * 16 + mrow) * 64 + sw);
#pragma unroll
            for (int mi = 0; mi < 2; ++mi)
#pragma unroll
                for (int nj = 0; nj < 4; ++nj)
                    acc[mi][nj] = MFMA16(af[mi], bfr[nj], acc[mi][nj]);
        }
    }

#pragma unroll
    for (int mi = 0; mi < 2; ++mi) {
#pragma unroll
        for (int nj = 0; nj < 4; ++nj) {
            const int col = n0 + nj * 16 + mrow;
#pragma unroll
            for (int r = 0; r < 4; ++r) {
                const int row = m0 + w * 32 + mi * 16 + quad * 4 + r;
                outf[row * EE + col] = acc[mi][nj][r] + bias[col];
            }
        }
    }
}

// ---------------------------------------------------------------------------
// Kernel 4: flash attention — R1 SIMPLIFICATION: split-K REMOVED (the
// split/combine machinery is the prime suspect for the run-to-run
// nondeterminism the pwire tripwire catches; this family had documented
// timing-sensitive failures at split-K=4).  One block = 256 q-rows x full
// K-range (32 K-tiles).  Softmax 1/l folded into epilogue (combine_kernel
// deleted).  Grid 256; bh = bid&31 so all 8 q-tiles of one (b,head) land on
// one XCD -> K/V L2-served after first fetch.
// Other structure unchanged (R11/R14 known-good): 32x32 MFMA, S^T form,
// register P^T, 64 q-cols/wave, K-tile 64, dbuf DMA, one barrier/iter, exp2.
// ---------------------------------------------------------------------------
__global__ __launch_bounds__(256, 2) void attn_kernel(
    const bf16* __restrict__ q, const bf16* __restrict__ k,
    const bf16* __restrict__ vt, bf16* __restrict__ o0) {
    __shared__ bf16 lds[16896];  // staging: Ks[2][4096] | Vs[2][4096] (16384);
                                 // epilogue reuses as 4 x (64 x 66)
    bf16* Ks = lds;
    bf16* Vs = lds + 8192;

    const int t = threadIdx.x;
    const int w = t >> 6, lane = t & 63;
    const int q32 = lane & 31, h = lane >> 5;
    const int bh = blockIdx.x & 31;   // 0..31  (same-bh blocks share XCD)
    const int qb = blockIdx.x >> 5;   // 0..7 (256-row q tiles)
    const int qr0 = qb * 256 + w * 64;

    // Q B-frags: qi in {0,1} covers q-cols qr0 + qi*32 + q32
    bf16x8 qf[2][4];
#pragma unroll
    for (int qi = 0; qi < 2; ++qi)
#pragma unroll
        for (int c = 0; c < 4; ++c)
            qf[qi][c] = *(const bf16x8*)(q + (size_t)(bh * SS + qr0 + qi * 32 + q32) * DD +
                                         c * 16 + h * 8);

    f32x16 oacc[2][2];
#pragma unroll
    for (int qi = 0; qi < 2; ++qi)
#pragma unroll
        for (int mf = 0; mf < 2; ++mf)
#pragma unroll
            for (int i = 0; i < 16; ++i) oacc[qi][mf][i] = 0.f;
    float lsum[2] = {0.f, 0.f};

    const int dr = lane >> 3;
    const int dcg = ((lane & 7) ^ dr) * 8;
    const bf16* kg = k + (size_t)bh * SS * DD;
    const bf16* vg = vt + (size_t)bh * DD * SS;
    const bf16* kgl = kg + (size_t)dr * DD + dcg;
    const bf16* vgl = vg + (size_t)(w * 16 + dr) * SS + dcg;

#pragma unroll
    for (int i = 0; i < 2; ++i) {
        const int rb = w * 16 + i * 8;
        gload16(kgl + (size_t)rb * DD, Ks + rb * 64);
        gload16(vgl + (size_t)(i * 8) * SS, Vs + rb * 64);
    }

    for (int kt = 0; kt < SS / 64; ++kt) {
        __syncthreads();
        if (kt < SS / 64 - 1) {
            const int nb = (kt + 1) & 1;
#pragma unroll
            for (int i = 0; i < 2; ++i) {
                const int rb = w * 16 + i * 8;
                gload16(kgl + (size_t)((kt + 1) * 64 + rb) * DD, Ks + nb * 4096 + rb * 64);
                gload16(vgl + (size_t)(i * 8) * SS + (kt + 1) * 64, Vs + nb * 4096 + rb * 64);
            }
        }
        const bf16* Kb = Ks + (kt & 1) * 4096;
        const bf16* Vb = Vs + (kt & 1) * 4096;

        // ---- S^T = K·Q^T : 8 K-frag reads feed 16 MFMA (both qi) ----
        f32x16 st[2][2];
#pragma unroll
        for (int qi = 0; qi < 2; ++qi)
#pragma unroll
            for (int mf = 0; mf < 2; ++mf)
#pragma unroll
                for (int i = 0; i < 16; ++i) st[qi][mf][i] = 0.f;
#pragma unroll
        for (int c = 0; c < 4; ++c) {
            const int sw = ((2 * c + h) ^ (q32 & 7)) * 8;
#pragma unroll
            for (int mf = 0; mf < 2; ++mf) {
                bf16x8 kf = *(const bf16x8*)(Kb + (mf * 32 + q32) * 64 + sw);
#pragma unroll
                for (int qi = 0; qi < 2; ++qi)
                    st[qi][mf] = MFMA32(kf, qf[qi][c], st[qi][mf]);
            }
        }

        // ---- p = exp2(s') (q carries log2e), pack ----
        u32 P32[2][2][8];
#pragma unroll
        for (int qi = 0; qi < 2; ++qi)
#pragma unroll
            for (int mf = 0; mf < 2; ++mf)
#pragma unroll
                for (int rp = 0; rp < 8; ++rp) {
                    float pa = __builtin_amdgcn_exp2f(st[qi][mf][2 * rp]);
                    float pb = __builtin_amdgcn_exp2f(st[qi][mf][2 * rp + 1]);
                    lsum[qi] += pa + pb;
                    P32[qi][mf][rp] = pkbf(pa, pb);
                }

        // ---- PV: 8 V-frag reads feed 16 MFMA (both qi) ----
#pragma unroll
        for (int c = 0; c < 4; ++c) {
            const int mfs = c >> 1;
            const int ro = (c & 1) * 4;
            union { u32 u[4]; bf16x8 v; } pb[2];
#pragma unroll
            for (int qi = 0; qi < 2; ++qi) {
                u32 vA0 = P32[qi][mfs][ro + 0], vA1 = P32[qi][mfs][ro + 1];
                u32 vB0 = P32[qi][mfs][ro + 2], vB1 = P32[qi][mfs][ro + 3];
                u32 prep0 = h ? vA0 : vB0;
                u32 prep1 = h ? vA1 : vB1;
                u32 sh0 = __shfl_xor(prep0, 32);
                u32 sh1 = __shfl_xor(prep1, 32);
                pb[qi].u[0] = h ? sh0 : vA0;
                pb[qi].u[1] = h ? sh1 : vA1;
                pb[qi].u[2] = h ? vB0 : sh0;
                pb[qi].u[3] = h ? vB1 : sh1;
            }
            const int sw = ((2 * c + h) ^ (q32 & 7)) * 8;
#pragma unroll
            for (int mf = 0; mf < 2; ++mf) {
                bf16x8 vf = *(const bf16x8*)(Vb + (mf * 32 + q32) * 64 + sw);
#pragma unroll
                for (int qi = 0; qi < 2; ++qi)
                    oacc[qi][mf] = MFMA32(vf, pb[qi].v, oacc[qi][mf]);
            }
        }
    }

    lsum[0] += __shfl_xor(lsum[0], 32);
    lsum[1] += __shfl_xor(lsum[1], 32);
    const float inv[2] = {1.f / lsum[0], 1.f / lsum[1]};

    // ---- epilogue: O^T regs (normalized) -> per-wave LDS transpose -> store
    __syncthreads();  // all waves done with staging buffers
    bf16* ob = lds + w * 4224;  // 64 rows x stride 66
#pragma unroll
    for (int qi = 0; qi < 2; ++qi)
#pragma unroll
        for (int mf = 0; mf < 2; ++mf)
#pragma unroll
            for (int rp = 0; rp < 8; ++rp) {
                const int d = 32 * mf + 2 * (rp & 1) + 8 * (rp >> 1) + 4 * h;
                *(u32*)(ob + (qi * 32 + q32) * 66 + d) =
                    pkbf(oacc[qi][mf][2 * rp] * inv[qi],
                         oacc[qi][mf][2 * rp + 1] * inv[qi]);
            }
    __syncthreads();

    const int b = bh >> 4, head = bh & 15;
    const int half = lane & 1;
#pragma unroll
    for (int p = 0; p < 2; ++p) {
        const int r = p * 32 + (lane >> 1);
#pragma unroll
        for (int i = 0; i < 4; ++i) {
            bf16x8 val = *(const bf16x8*)(ob + r * 66 + half * 32 + i * 8);
            *(bf16x8*)(o0 + (size_t)(b * SS + qr0 + r) * EE + head * DD +
                       half * 32 + i * 8) = val;
        }
    }
}

// ---------------------------------------------------------------------------
// R1: single scratch layout, everything in d_ws (40.0 MiB < the 40.5 MiB the
// previously-passing session used, so it fits).  d_out is written exactly
// once, by gemm_o.  split-K/combine/lws deleted.
// ---------------------------------------------------------------------------
extern "C" void kernel_launch(void* const* d_in, const int* in_sizes, int n_in,
                              void* d_out, int out_size, void* d_ws, size_t ws_size,
                              hipStream_t stream) {
    const float* query = (const float*)d_in[0];
    const float* xi    = (const float*)d_in[1];
    const float* Wq = (const float*)d_in[2];  const float* bq = (const float*)d_in[3];
    const float* Wk = (const float*)d_in[4];  const float* bk = (const float*)d_in[5];
    const float* Wv = (const float*)d_in[6];  const float* bv = (const float*)d_in[7];
    const float* Wo = (const float*)d_in[8];  const float* bo = (const float*)d_in[9];
    const float* ew1 = (const float*)d_in[10]; const float* eb1 = (const float*)d_in[11];
    const float* lng = (const float*)d_in[12]; const float* lnb = (const float*)d_in[13];
    const float* ew2 = (const float*)d_in[14]; const float* eb2 = (const float*)d_in[15];
    const float* gate = (const float*)d_in[16];
    float* out = (float*)d_out;

    char* ws = (char*)d_ws;
    const size_t SZ = (size_t)MM * EE * sizeof(bf16);   // 8 MB
    const size_t WSZ = (size_t)EE * EE * sizeof(bf16);  // 2 MB per transposed weight

    bf16* queryc = (bf16*)(ws);            // dead after gemm_qkv
    bf16* p0     = (bf16*)(ws);            // attn output overlays queryc
    bf16* qws    = (bf16*)(ws + SZ);
    bf16* kws    = (bf16*)(ws + 2 * SZ);
    bf16* vtws   = (bf16*)(ws + 3 * SZ);
    bf16* wqT    = (bf16*)(ws + 4 * SZ);
    bf16* wkT    = (bf16*)(ws + 4 * SZ + WSZ);
    bf16* wvT    = (bf16*)(ws + 4 * SZ + 2 * WSZ);
    bf16* woT    = (bf16*)(ws + 4 * SZ + 3 * WSZ);
    float* adaptws = (float*)(ws + 4 * SZ + 4 * WSZ);

    prep_kernel<<<3074, 256, 0, stream>>>(query, queryc, Wq, Wk, Wv, Wo,
                                          wqT, wkT, wvT, woT,
                                          xi, ew1, eb1, lng, lnb, ew2, eb2, gate,
                                          adaptws);

    // combined QK (512) + V^T (256) = 768 blocks = 3/CU
    gemm_qkv<<<768, 256, 0, stream>>>(queryc, wqT, wvT, bq, bk, bv, adaptws,
                                      qws, vtws);

    // 32 bh x 8 q-tiles = 256 blocks of 256 threads (full K-range per block)
    attn_kernel<<<256, 256, 0, stream>>>(qws, kws, vtws, p0);

    gemm_o<<<dim3(MM / 128, EE / 64), 256, 0, stream>>>(p0, woT, bo, out);
}

// Round 3
// 217.078 us; speedup vs baseline: 1.0056x; 1.0056x over previous
//
#include <hip/hip_runtime.h>

typedef __bf16 bf16;
typedef __attribute__((ext_vector_type(8))) __bf16 bf16x8;
typedef __attribute__((ext_vector_type(4))) float f32x4;
typedef __attribute__((ext_vector_type(16))) float f32x16;
typedef unsigned int u32;

#define MFMA16(a, b, c) __builtin_amdgcn_mfma_f32_16x16x32_bf16((a), (b), (c), 0, 0, 0)
#define MFMA32(a, b, c) __builtin_amdgcn_mfma_f32_32x32x16_bf16((a), (b), (c), 0, 0, 0)

// Problem constants
#define BB 2
#define SS 2048
#define EE 1024
#define HH 16
#define DD 64
#define MM (BB * SS)  // 4096

__device__ inline f32x4 zero4() {
    f32x4 z; z.x = 0.f; z.y = 0.f; z.z = 0.f; z.w = 0.f; return z;
}

// async global->LDS DMA, 16B per lane.  LDS dest = wave-uniform base + lane*16.
__device__ __forceinline__ void gload16(const bf16* g, bf16* l) {
    __builtin_amdgcn_global_load_lds(
        (const __attribute__((address_space(1))) u32*)(const void*)g,
        (__attribute__((address_space(3))) u32*)(void*)l,
        16, 0, 0);
}

__device__ __forceinline__ u32 pkbf(float a, float b) {
    union { __bf16 h; unsigned short s; } ua, ub;
    ua.h = (__bf16)a; ub.h = (__bf16)b;
    return (u32)ua.s | ((u32)ub.s << 16);
}

// ---------------------------------------------------------------------------
// Kernel 1: fused prep.
// ---------------------------------------------------------------------------
__global__ __launch_bounds__(256) void prep_kernel(
    const float* __restrict__ query, bf16* __restrict__ qc,
    const float* __restrict__ s0, const float* __restrict__ s1,
    const float* __restrict__ s2, const float* __restrict__ s3,
    bf16* __restrict__ d0, bf16* __restrict__ d1,
    bf16* __restrict__ d2, bf16* __restrict__ d3,
    const float* __restrict__ xi, const float* __restrict__ w1,
    const float* __restrict__ b1, const float* __restrict__ lng,
    const float* __restrict__ lnb, const float* __restrict__ w2,
    const float* __restrict__ b2, const float* __restrict__ gate,
    float* __restrict__ adapt) {
    __shared__ bf16 tile[64 * 72];
    const int bid = blockIdx.x;
    const int t = threadIdx.x;

    if (bid < 2048) {
        const int i = (bid * 256 + t) * 8;
        float4 a = *(const float4*)(query + i);
        float4 b = *(const float4*)(query + i + 4);
        bf16 tmp[8];
        tmp[0] = (bf16)a.x; tmp[1] = (bf16)a.y; tmp[2] = (bf16)a.z; tmp[3] = (bf16)a.w;
        tmp[4] = (bf16)b.x; tmp[5] = (bf16)b.y; tmp[6] = (bf16)b.z; tmp[7] = (bf16)b.w;
        *(uint4*)(qc + i) = *(uint4*)tmp;
    } else if (bid < 3072) {
        const int m = (bid - 2048) >> 8;
        const int idx0 = (bid - 2048) & 255;
        const float* W = (m == 0) ? s0 : (m == 1) ? s1 : (m == 2) ? s2 : s3;
        bf16* Wt = (m == 0) ? d0 : (m == 1) ? d1 : (m == 2) ? d2 : d3;
        const int k0 = (idx0 >> 4) * 64, n0 = (idx0 & 15) * 64;
#pragma unroll
        for (int i = 0; i < 2; ++i) {
            int idx = i * 256 + t;
            int r = idx >> 3, c = (idx & 7) * 8;
            float4 a = *(const float4*)(W + (k0 + r) * EE + n0 + c);
            float4 b = *(const float4*)(W + (k0 + r) * EE + n0 + c + 4);
            bf16 tmp[8];
            tmp[0] = (bf16)a.x; tmp[1] = (bf16)a.y; tmp[2] = (bf16)a.z; tmp[3] = (bf16)a.w;
            tmp[4] = (bf16)b.x; tmp[5] = (bf16)b.y; tmp[6] = (bf16)b.z; tmp[7] = (bf16)b.w;
            *(uint4*)(tile + r * 72 + c) = *(uint4*)tmp;
        }
        __syncthreads();
#pragma unroll
        for (int i = 0; i < 2; ++i) {
            int idx = i * 256 + t;
            int n = idx >> 3, kc = (idx & 7) * 8;
            bf16 tmp[8];
#pragma unroll
            for (int j = 0; j < 8; ++j) tmp[j] = tile[(kc + j) * 72 + n];
            *(uint4*)(Wt + (n0 + n) * EE + k0 + kc) = *(uint4*)tmp;
        }
    } else {
        const int b = bid - 3072;
        float* xs = (float*)tile;
        if (t < 64) {
            const float xiv = xi[b];
            float xv = 0.f;
            if (t < 32) xv = xiv * w1[t] + b1[t];
            float sm = xv;
            for (int off = 1; off < 32; off <<= 1) sm += __shfl_xor(sm, off);
            const float mu = sm * (1.f / 32.f);
            float dv = (t < 32) ? (xv - mu) : 0.f;
            float s2 = dv * dv;
            for (int off = 1; off < 32; off <<= 1) s2 += __shfl_xor(s2, off);
            const float var = s2 * (1.f / 32.f);
            if (t < 32) {
                float xn = (xv - mu) * rsqrtf(var + 1e-5f) * lng[t] + lnb[t];
                float ge = 0.5f * xn * (1.f + erff(xn * 0.70710678118654752f));
                xs[t] = ge;
            }
        }
        __syncthreads();
        if (t < 64) {
            float acc = b2[t];
            for (int j = 0; j < 32; ++j) acc += xs[j] * w2[j * DD + t];
            for (int h = 0; h < HH; ++h) {
                float sg = 1.f / (1.f + __expf(-gate[h]));
                adapt[(b * HH + h) * DD + t] = 1.f + sg * acc;
            }
        }
    }
}

// ---------------------------------------------------------------------------
// Kernel 2: QKV GEMM — 128x128 tile, BK=32, dbuf DMA, one barrier/iter.
// q-scale folds 0.125*log2(e) so attention uses bare v_exp_f32 (exp2).
// ---------------------------------------------------------------------------
__global__ __launch_bounds__(256, 3) void gemm_qkv(
    const bf16* __restrict__ Aq, const bf16* __restrict__ Bqk,
    const bf16* __restrict__ Av,
    const float* __restrict__ bias, const float* __restrict__ bias2,
    const float* __restrict__ bias3, const float* __restrict__ adapt,
    bf16* __restrict__ outqk, bf16* __restrict__ outvt) {
    __shared__ bf16 As[2 * 128 * 32];
    __shared__ bf16 Bs[2 * 128 * 32];

    const int t = threadIdx.x;
    const int w = t >> 6, lane = t & 63;
    const int mrow = lane & 15, quad = lane >> 4;
    const int wm = (w & 1) * 64, wn = (w >> 1) * 64;

    int md, bx, by;
    const bf16 *Ap, *Bp;
    int bid = blockIdx.x;
    if (bid < 512) { md = 5; bx = bid & 31; by = bid >> 5; Ap = Aq; Bp = Bqk; }
    else { md = 4; bid -= 512; bx = bid & 7; by = bid >> 3; Ap = Av; Bp = Aq; }
    const int m0 = bx * 128, n0 = by * 128;

    f32x4 acc[4][4];
#pragma unroll
    for (int i = 0; i < 4; ++i)
#pragma unroll
        for (int j = 0; j < 4; ++j) acc[i][j] = zero4();

    const int dr = lane >> 2;
    const int dcg = ((lane & 3) ^ (dr & 3)) * 8;
    const bf16* Ag = Ap + (size_t)(m0 + w * 16 + dr) * EE + dcg;
    const bf16* Bg = Bp + (size_t)(n0 + w * 16 + dr) * EE + dcg;
    bf16* Al = As + (w * 16) * 32;
    bf16* Bl = Bs + (w * 16) * 32;

    gload16(Ag, Al);
    gload16(Ag + 64 * EE, Al + 64 * 32);
    gload16(Bg, Bl);
    gload16(Bg + 64 * EE, Bl + 64 * 32);

    for (int kt = 0; kt < 32; ++kt) {
        __syncthreads();
        if (kt < 31) {
            const int kn = (kt + 1) * 32;
            const int nb = (kt + 1) & 1;
            gload16(Ag + kn, Al + nb * 4096);
            gload16(Ag + 64 * EE + kn, Al + nb * 4096 + 64 * 32);
            gload16(Bg + kn, Bl + nb * 4096);
            gload16(Bg + 64 * EE + kn, Bl + nb * 4096 + 64 * 32);
        }
        const bf16* Ab = As + (kt & 1) * 4096;
        const bf16* Bb = Bs + (kt & 1) * 4096;
        const int sw = (quad ^ (mrow & 3)) * 8;
        bf16x8 af[4], bfr[4];
#pragma unroll
        for (int i = 0; i < 4; ++i)
            af[i] = *(const bf16x8*)(Ab + (wm + i * 16 + mrow) * 32 + sw);
#pragma unroll
        for (int j = 0; j < 4; ++j)
            bfr[j] = *(const bf16x8*)(Bb + (wn + j * 16 + mrow) * 32 + sw);
#pragma unroll
        for (int i = 0; i < 4; ++i)
#pragma unroll
            for (int j = 0; j < 4; ++j)
                acc[i][j] = MFMA16(af[i], bfr[j], acc[i][j]);
    }

#pragma unroll
    for (int i = 0; i < 4; ++i) {
#pragma unroll
        for (int j = 0; j < 4; ++j) {
            const int col = n0 + wn + j * 16 + mrow;
#pragma unroll
            for (int r = 0; r < 4; ++r) {
                const int row = m0 + wm + i * 16 + quad * 4 + r;
                float v = acc[i][j][r];
                if (md == 4) {
                    v += bias3[row];
                    const int h = row >> 6, d = row & 63;
                    const int b = col >> 11, s = col & (SS - 1);
                    outvt[(((b * HH + h) * DD + d) * SS) + s] = (bf16)v;
                } else {
                    const int m2 = col >> 10;
                    const int cl = col & 1023;
                    const int h = cl >> 6, d = cl & 63;
                    const int b = row >> 11, s = row & (SS - 1);
                    v += (m2 ? bias2[cl] : bias[cl]);
                    v *= adapt[(b * HH + h) * DD + d];
                    // q: 1/sqrt(64) * log2(e) folded (attn uses exp2)
                    if (!m2) v *= 0.18033688011113811f;
                    outqk[(size_t)m2 * MM * EE + ((b * HH + h) * SS + s) * DD + d] = (bf16)v;
                }
            }
        }
    }
}

// ---------------------------------------------------------------------------
// Kernel 3: final GEMM.
// ---------------------------------------------------------------------------
__global__ __launch_bounds__(256, 3) void gemm_o(
    const bf16* __restrict__ A, const bf16* __restrict__ Bt,
    const float* __restrict__ bias, float* __restrict__ outf) {
    __shared__ bf16 As[2 * 128 * 64];
    __shared__ bf16 Bs[2 * 64 * 64];

    const int t = threadIdx.x;
    const int w = t >> 6, lane = t & 63;
    const int mrow = lane & 15, quad = lane >> 4;
    const int m0 = blockIdx.x * 128, n0 = blockIdx.y * 64;

    f32x4 acc[2][4];
#pragma unroll
    for (int i = 0; i < 2; ++i)
#pragma unroll
        for (int j = 0; j < 4; ++j) acc[i][j] = zero4();

    const int grow = lane >> 3;
    const int gsw = ((lane & 7) ^ grow) * 8;
    const bf16* Ag = A + (size_t)(m0 + w * 32 + grow) * EE + gsw;
    const bf16* Bg = Bt + (size_t)(n0 + w * 16 + grow) * EE + gsw;
    bf16* Al = As + (w * 32) * 64;
    bf16* Bl = Bs + (w * 16) * 64;

#pragma unroll
    for (int i = 0; i < 4; ++i) gload16(Ag + i * 8 * EE, Al + i * 8 * 64);
#pragma unroll
    for (int i = 0; i < 2; ++i) gload16(Bg + i * 8 * EE, Bl + i * 8 * 64);

    for (int kt = 0; kt < 16; ++kt) {
        __syncthreads();
        if (kt < 15) {
            const int kn = (kt + 1) * 64;
            const int nb = (kt + 1) & 1;
#pragma unroll
            for (int i = 0; i < 4; ++i)
                gload16(Ag + i * 8 * EE + kn, Al + nb * 8192 + i * 8 * 64);
#pragma unroll
            for (int i = 0; i < 2; ++i)
                gload16(Bg + i * 8 * EE + kn, Bl + nb * 4096 + i * 8 * 64);
        }
        const bf16* Ab = As + (kt & 1) * 8192;
        const bf16* Bb = Bs + (kt & 1) * 4096;
#pragma unroll
        for (int ks = 0; ks < 2; ++ks) {
            const int cg = ks * 4 + quad;
            const int sw = (cg ^ (mrow & 7)) * 8;
            bf16x8 af[2], bfr[4];
#pragma unroll
            for (int mi = 0; mi < 2; ++mi)
                af[mi] = *(const bf16x8*)(Ab + (w * 32 + mi * 16 + mrow) * 64 + sw);
#pragma unroll
            for (int nj = 0; nj < 4; ++nj)
                bfr[nj] = *(const bf16x8*)(Bb + (nj * 16 + mrow) * 64 + sw);
#pragma unroll
            for (int mi = 0; mi < 2; ++mi)
#pragma unroll
                for (int nj = 0; nj < 4; ++nj)
                    acc[mi][nj] = MFMA16(af[mi], bfr[nj], acc[mi][nj]);
        }
    }

#pragma unroll
    for (int mi = 0; mi < 2; ++mi) {
#pragma unroll
        for (int nj = 0; nj < 4; ++nj) {
            const int col = n0 + nj * 16 + mrow;
#pragma unroll
            for (int r = 0; r < 4; ++r) {
                const int row = m0 + w * 32 + mi * 16 + quad * 4 + r;
                outf[row * EE + col] = acc[mi][nj][r] + bias[col];
            }
        }
    }
}

// ---------------------------------------------------------------------------
// Kernel 4: flash attention.  R2: q-tile halved to 128 rows/block (32
// q-cols/wave, qi dimension removed) -> grid 512 = 2 blocks/CU = 8 waves/CU.
// R2 theory: R1's 256-block grid gave 1 block/CU (Occupancy 9.8%); every
// barrier+DMA-drain stalled the whole CU (MfmaUtil 21.5, VALUBusy 36, ~43%
// idle).  Two blocks/CU interleave: one computes while the other drains.
// Total MFMA work unchanged; K/V restaged 2x but L2-served (4 bh/XCD = 2 MB
// < 4 MB L2).  bh = bid&31 keeps all 16 q-tiles of one (b,head) on one XCD.
// Known-good structure retained: 32x32 MFMA, S^T form, register P^T, K-tile
// 64, dbuf DMA, one barrier/iter, exp2 softmax, 1/l folded in epilogue.
// Dead ends (do not re-attempt): split-K (R12/R13 + R0/R1 nondeterminism),
// K-tile 32 (partial-line HBM blowup), K-tile 128 (spill), forced 4 blk/CU.
// ---------------------------------------------------------------------------
__global__ __launch_bounds__(256, 2) void attn_kernel(
    const bf16* __restrict__ q, const bf16* __restrict__ k,
    const bf16* __restrict__ vt, bf16* __restrict__ o0) {
    __shared__ bf16 lds[16384];  // staging: Ks[2][4096] | Vs[2][4096];
                                 // epilogue reuses first 8448 as 4 x (32 x 66)
    bf16* Ks = lds;
    bf16* Vs = lds + 8192;

    const int t = threadIdx.x;
    const int w = t >> 6, lane = t & 63;
    const int q32 = lane & 31, h = lane >> 5;
    const int bh = blockIdx.x & 31;   // 0..31  (same-bh blocks share XCD)
    const int qb = blockIdx.x >> 5;   // 0..15 (128-row q tiles)
    const int qr0 = qb * 128 + w * 32;

    // Q B-frags: q-cols qr0 + q32
    bf16x8 qf[4];
#pragma unroll
    for (int c = 0; c < 4; ++c)
        qf[c] = *(const bf16x8*)(q + (size_t)(bh * SS + qr0 + q32) * DD + c * 16 + h * 8);

    f32x16 oacc[2];
#pragma unroll
    for (int mf = 0; mf < 2; ++mf)
#pragma unroll
        for (int i = 0; i < 16; ++i) oacc[mf][i] = 0.f;
    float lsum = 0.f;

    const int dr = lane >> 3;
    const int dcg = ((lane & 7) ^ dr) * 8;
    const bf16* kg = k + (size_t)bh * SS * DD;
    const bf16* vg = vt + (size_t)bh * DD * SS;
    const bf16* kgl = kg + (size_t)dr * DD + dcg;
    const bf16* vgl = vg + (size_t)(w * 16 + dr) * SS + dcg;

#pragma unroll
    for (int i = 0; i < 2; ++i) {
        const int rb = w * 16 + i * 8;
        gload16(kgl + (size_t)rb * DD, Ks + rb * 64);
        gload16(vgl + (size_t)(i * 8) * SS, Vs + rb * 64);
    }

    for (int kt = 0; kt < SS / 64; ++kt) {
        __syncthreads();
        if (kt < SS / 64 - 1) {
            const int nb = (kt + 1) & 1;
#pragma unroll
            for (int i = 0; i < 2; ++i) {
                const int rb = w * 16 + i * 8;
                gload16(kgl + (size_t)((kt + 1) * 64 + rb) * DD, Ks + nb * 4096 + rb * 64);
                gload16(vgl + (size_t)(i * 8) * SS + (kt + 1) * 64, Vs + nb * 4096 + rb * 64);
            }
        }
        const bf16* Kb = Ks + (kt & 1) * 4096;
        const bf16* Vb = Vs + (kt & 1) * 4096;

        // ---- S^T = K·Q^T : 8 K-frag reads feed 8 MFMA ----
        f32x16 st[2];
#pragma unroll
        for (int mf = 0; mf < 2; ++mf)
#pragma unroll
            for (int i = 0; i < 16; ++i) st[mf][i] = 0.f;
#pragma unroll
        for (int c = 0; c < 4; ++c) {
            const int sw = ((2 * c + h) ^ (q32 & 7)) * 8;
#pragma unroll
            for (int mf = 0; mf < 2; ++mf) {
                bf16x8 kf = *(const bf16x8*)(Kb + (mf * 32 + q32) * 64 + sw);
                st[mf] = MFMA32(kf, qf[c], st[mf]);
            }
        }

        // ---- p = exp2(s') (q carries log2e), pack ----
        u32 P32[2][8];
#pragma unroll
        for (int mf = 0; mf < 2; ++mf)
#pragma unroll
            for (int rp = 0; rp < 8; ++rp) {
                float pa = __builtin_amdgcn_exp2f(st[mf][2 * rp]);
                float pb = __builtin_amdgcn_exp2f(st[mf][2 * rp + 1]);
                lsum += pa + pb;
                P32[mf][rp] = pkbf(pa, pb);
            }

        // ---- PV: 8 V-frag reads feed 8 MFMA ----
#pragma unroll
        for (int c = 0; c < 4; ++c) {
            const int mfs = c >> 1;
            const int ro = (c & 1) * 4;
            union { u32 u[4]; bf16x8 v; } pb;
            {
                u32 vA0 = P32[mfs][ro + 0], vA1 = P32[mfs][ro + 1];
                u32 vB0 = P32[mfs][ro + 2], vB1 = P32[mfs][ro + 3];
                u32 prep0 = h ? vA0 : vB0;
                u32 prep1 = h ? vA1 : vB1;
                u32 sh0 = __shfl_xor(prep0, 32);
                u32 sh1 = __shfl_xor(prep1, 32);
                pb.u[0] = h ? sh0 : vA0;
                pb.u[1] = h ? sh1 : vA1;
                pb.u[2] = h ? vB0 : sh0;
                pb.u[3] = h ? vB1 : sh1;
            }
            const int sw = ((2 * c + h) ^ (q32 & 7)) * 8;
#pragma unroll
            for (int mf = 0; mf < 2; ++mf) {
                bf16x8 vf = *(const bf16x8*)(Vb + (mf * 32 + q32) * 64 + sw);
                oacc[mf] = MFMA32(vf, pb.v, oacc[mf]);
            }
        }
    }

    lsum += __shfl_xor(lsum, 32);
    const float inv = 1.f / lsum;

    // ---- epilogue: O^T regs (normalized) -> per-wave LDS transpose -> store
    __syncthreads();  // all waves done with staging buffers
    bf16* ob = lds + w * 2112;  // 32 rows x stride 66
#pragma unroll
    for (int mf = 0; mf < 2; ++mf)
#pragma unroll
        for (int rp = 0; rp < 8; ++rp) {
            const int d = 32 * mf + 2 * (rp & 1) + 8 * (rp >> 1) + 4 * h;
            *(u32*)(ob + q32 * 66 + d) =
                pkbf(oacc[mf][2 * rp] * inv, oacc[mf][2 * rp + 1] * inv);
        }
    __syncthreads();

    const int b = bh >> 4, head = bh & 15;
    const int half = lane & 1;
    const int r = lane >> 1;
#pragma unroll
    for (int i = 0; i < 4; ++i) {
        bf16x8 val = *(const bf16x8*)(ob + r * 66 + half * 32 + i * 8);
        *(bf16x8*)(o0 + (size_t)(b * SS + qr0 + r) * EE + head * DD +
                   half * 32 + i * 8) = val;
    }
}

// ---------------------------------------------------------------------------
// Single scratch layout, everything in d_ws (40 MiB).  d_out written exactly
// once, by gemm_o.
// ---------------------------------------------------------------------------
extern "C" void kernel_launch(void* const* d_in, const int* in_sizes, int n_in,
                              void* d_out, int out_size, void* d_ws, size_t ws_size,
                              hipStream_t stream) {
    const float* query = (const float*)d_in[0];
    const float* xi    = (const float*)d_in[1];
    const float* Wq = (const float*)d_in[2];  const float* bq = (const float*)d_in[3];
    const float* Wk = (const float*)d_in[4];  const float* bk = (const float*)d_in[5];
    const float* Wv = (const float*)d_in[6];  const float* bv = (const float*)d_in[7];
    const float* Wo = (const float*)d_in[8];  const float* bo = (const float*)d_in[9];
    const float* ew1 = (const float*)d_in[10]; const float* eb1 = (const float*)d_in[11];
    const float* lng = (const float*)d_in[12]; const float* lnb = (const float*)d_in[13];
    const float* ew2 = (const float*)d_in[14]; const float* eb2 = (const float*)d_in[15];
    const float* gate = (const float*)d_in[16];
    float* out = (float*)d_out;

    char* ws = (char*)d_ws;
    const size_t SZ = (size_t)MM * EE * sizeof(bf16);   // 8 MB
    const size_t WSZ = (size_t)EE * EE * sizeof(bf16);  // 2 MB per transposed weight

    bf16* queryc = (bf16*)(ws);            // dead after gemm_qkv
    bf16* p0     = (bf16*)(ws);            // attn output overlays queryc
    bf16* qws    = (bf16*)(ws + SZ);
    bf16* kws    = (bf16*)(ws + 2 * SZ);
    bf16* vtws   = (bf16*)(ws + 3 * SZ);
    bf16* wqT    = (bf16*)(ws + 4 * SZ);
    bf16* wkT    = (bf16*)(ws + 4 * SZ + WSZ);
    bf16* wvT    = (bf16*)(ws + 4 * SZ + 2 * WSZ);
    bf16* woT    = (bf16*)(ws + 4 * SZ + 3 * WSZ);
    float* adaptws = (float*)(ws + 4 * SZ + 4 * WSZ);

    prep_kernel<<<3074, 256, 0, stream>>>(query, queryc, Wq, Wk, Wv, Wo,
                                          wqT, wkT, wvT, woT,
                                          xi, ew1, eb1, lng, lnb, ew2, eb2, gate,
                                          adaptws);

    // combined QK (512) + V^T (256) = 768 blocks = 3/CU
    gemm_qkv<<<768, 256, 0, stream>>>(queryc, wqT, wvT, bq, bk, bv, adaptws,
                                      qws, vtws);

    // 32 bh x 16 q-tiles = 512 blocks of 256 threads (full K-range per block)
    attn_kernel<<<512, 256, 0, stream>>>(qws, kws, vtws, p0);

    gemm_o<<<dim3(MM / 128, EE / 64), 256, 0, stream>>>(p0, woT, bo, out);
}

// Round 4
// 215.732 us; speedup vs baseline: 1.0119x; 1.0062x over previous
//
#include <hip/hip_runtime.h>

typedef __bf16 bf16;
typedef __attribute__((ext_vector_type(8))) __bf16 bf16x8;
typedef __attribute__((ext_vector_type(4))) float f32x4;
typedef __attribute__((ext_vector_type(16))) float f32x16;
typedef unsigned int u32;

#define MFMA16(a, b, c) __builtin_amdgcn_mfma_f32_16x16x32_bf16((a), (b), (c), 0, 0, 0)
#define MFMA32(a, b, c) __builtin_amdgcn_mfma_f32_32x32x16_bf16((a), (b), (c), 0, 0, 0)

// Problem constants
#define BB 2
#define SS 2048
#define EE 1024
#define HH 16
#define DD 64
#define MM (BB * SS)  // 4096

__device__ inline f32x4 zero4() {
    f32x4 z; z.x = 0.f; z.y = 0.f; z.z = 0.f; z.w = 0.f; return z;
}

// async global->LDS DMA, 16B per lane.  LDS dest = wave-uniform base + lane*16.
__device__ __forceinline__ void gload16(const bf16* g, bf16* l) {
    __builtin_amdgcn_global_load_lds(
        (const __attribute__((address_space(1))) u32*)(const void*)g,
        (__attribute__((address_space(3))) u32*)(void*)l,
        16, 0, 0);
}

__device__ __forceinline__ u32 pkbf(float a, float b) {
    union { __bf16 h; unsigned short s; } ua, ub;
    ua.h = (__bf16)a; ub.h = (__bf16)b;
    return (u32)ua.s | ((u32)ub.s << 16);
}

// ---------------------------------------------------------------------------
// Kernel 1: fused prep.
// ---------------------------------------------------------------------------
__global__ __launch_bounds__(256) void prep_kernel(
    const float* __restrict__ query, bf16* __restrict__ qc,
    const float* __restrict__ s0, const float* __restrict__ s1,
    const float* __restrict__ s2, const float* __restrict__ s3,
    bf16* __restrict__ d0, bf16* __restrict__ d1,
    bf16* __restrict__ d2, bf16* __restrict__ d3,
    const float* __restrict__ xi, const float* __restrict__ w1,
    const float* __restrict__ b1, const float* __restrict__ lng,
    const float* __restrict__ lnb, const float* __restrict__ w2,
    const float* __restrict__ b2, const float* __restrict__ gate,
    float* __restrict__ adapt) {
    __shared__ bf16 tile[64 * 72];
    const int bid = blockIdx.x;
    const int t = threadIdx.x;

    if (bid < 2048) {
        const int i = (bid * 256 + t) * 8;
        float4 a = *(const float4*)(query + i);
        float4 b = *(const float4*)(query + i + 4);
        bf16 tmp[8];
        tmp[0] = (bf16)a.x; tmp[1] = (bf16)a.y; tmp[2] = (bf16)a.z; tmp[3] = (bf16)a.w;
        tmp[4] = (bf16)b.x; tmp[5] = (bf16)b.y; tmp[6] = (bf16)b.z; tmp[7] = (bf16)b.w;
        *(uint4*)(qc + i) = *(uint4*)tmp;
    } else if (bid < 3072) {
        const int m = (bid - 2048) >> 8;
        const int idx0 = (bid - 2048) & 255;
        const float* W = (m == 0) ? s0 : (m == 1) ? s1 : (m == 2) ? s2 : s3;
        bf16* Wt = (m == 0) ? d0 : (m == 1) ? d1 : (m == 2) ? d2 : d3;
        const int k0 = (idx0 >> 4) * 64, n0 = (idx0 & 15) * 64;
#pragma unroll
        for (int i = 0; i < 2; ++i) {
            int idx = i * 256 + t;
            int r = idx >> 3, c = (idx & 7) * 8;
            float4 a = *(const float4*)(W + (k0 + r) * EE + n0 + c);
            float4 b = *(const float4*)(W + (k0 + r) * EE + n0 + c + 4);
            bf16 tmp[8];
            tmp[0] = (bf16)a.x; tmp[1] = (bf16)a.y; tmp[2] = (bf16)a.z; tmp[3] = (bf16)a.w;
            tmp[4] = (bf16)b.x; tmp[5] = (bf16)b.y; tmp[6] = (bf16)b.z; tmp[7] = (bf16)b.w;
            *(uint4*)(tile + r * 72 + c) = *(uint4*)tmp;
        }
        __syncthreads();
#pragma unroll
        for (int i = 0; i < 2; ++i) {
            int idx = i * 256 + t;
            int n = idx >> 3, kc = (idx & 7) * 8;
            bf16 tmp[8];
#pragma unroll
            for (int j = 0; j < 8; ++j) tmp[j] = tile[(kc + j) * 72 + n];
            *(uint4*)(Wt + (n0 + n) * EE + k0 + kc) = *(uint4*)tmp;
        }
    } else {
        const int b = bid - 3072;
        float* xs = (float*)tile;
        if (t < 64) {
            const float xiv = xi[b];
            float xv = 0.f;
            if (t < 32) xv = xiv * w1[t] + b1[t];
            float sm = xv;
            for (int off = 1; off < 32; off <<= 1) sm += __shfl_xor(sm, off);
            const float mu = sm * (1.f / 32.f);
            float dv = (t < 32) ? (xv - mu) : 0.f;
            float s2 = dv * dv;
            for (int off = 1; off < 32; off <<= 1) s2 += __shfl_xor(s2, off);
            const float var = s2 * (1.f / 32.f);
            if (t < 32) {
                float xn = (xv - mu) * rsqrtf(var + 1e-5f) * lng[t] + lnb[t];
                float ge = 0.5f * xn * (1.f + erff(xn * 0.70710678118654752f));
                xs[t] = ge;
            }
        }
        __syncthreads();
        if (t < 64) {
            float acc = b2[t];
            for (int j = 0; j < 32; ++j) acc += xs[j] * w2[j * DD + t];
            for (int h = 0; h < HH; ++h) {
                float sg = 1.f / (1.f + __expf(-gate[h]));
                adapt[(b * HH + h) * DD + t] = 1.f + sg * acc;
            }
        }
    }
}

// ---------------------------------------------------------------------------
// Kernel 2: QKV GEMM — 128x128 tile, BK=32, dbuf DMA, one barrier/iter.
// q-scale folds 0.125*log2(e) so attention uses bare v_exp_f32 (exp2).
// R4: K and V^T outputs are written in a PERMUTED TILE LAYOUT
//   idx = bh*131072 + kt*4096 + mf*2048 + c*512 + lane*8 + j
// so attn's MFMA fragments become single fully-coalesced 1KB wave loads
// (lane*16B consecutive), enabling the LDS-free attention kernel.
//   K:  s = kt*64 + mf*32 + (lane&31), d = c*16 + (lane>>5)*8 + j
//   V^T: d = mf*32 + (lane&31),        s = kt*64 + c*16 + (lane>>5)*8 + j
// ---------------------------------------------------------------------------
__global__ __launch_bounds__(256, 3) void gemm_qkv(
    const bf16* __restrict__ Aq, const bf16* __restrict__ Bqk,
    const bf16* __restrict__ Av,
    const float* __restrict__ bias, const float* __restrict__ bias2,
    const float* __restrict__ bias3, const float* __restrict__ adapt,
    bf16* __restrict__ outqk, bf16* __restrict__ outvt) {
    __shared__ bf16 As[2 * 128 * 32];
    __shared__ bf16 Bs[2 * 128 * 32];

    const int t = threadIdx.x;
    const int w = t >> 6, lane = t & 63;
    const int mrow = lane & 15, quad = lane >> 4;
    const int wm = (w & 1) * 64, wn = (w >> 1) * 64;

    int md, bx, by;
    const bf16 *Ap, *Bp;
    int bid = blockIdx.x;
    if (bid < 512) { md = 5; bx = bid & 31; by = bid >> 5; Ap = Aq; Bp = Bqk; }
    else { md = 4; bid -= 512; bx = bid & 7; by = bid >> 3; Ap = Av; Bp = Aq; }
    const int m0 = bx * 128, n0 = by * 128;

    f32x4 acc[4][4];
#pragma unroll
    for (int i = 0; i < 4; ++i)
#pragma unroll
        for (int j = 0; j < 4; ++j) acc[i][j] = zero4();

    const int dr = lane >> 2;
    const int dcg = ((lane & 3) ^ (dr & 3)) * 8;
    const bf16* Ag = Ap + (size_t)(m0 + w * 16 + dr) * EE + dcg;
    const bf16* Bg = Bp + (size_t)(n0 + w * 16 + dr) * EE + dcg;
    bf16* Al = As + (w * 16) * 32;
    bf16* Bl = Bs + (w * 16) * 32;

    gload16(Ag, Al);
    gload16(Ag + 64 * EE, Al + 64 * 32);
    gload16(Bg, Bl);
    gload16(Bg + 64 * EE, Bl + 64 * 32);

    for (int kt = 0; kt < 32; ++kt) {
        __syncthreads();
        if (kt < 31) {
            const int kn = (kt + 1) * 32;
            const int nb = (kt + 1) & 1;
            gload16(Ag + kn, Al + nb * 4096);
            gload16(Ag + 64 * EE + kn, Al + nb * 4096 + 64 * 32);
            gload16(Bg + kn, Bl + nb * 4096);
            gload16(Bg + 64 * EE + kn, Bl + nb * 4096 + 64 * 32);
        }
        const bf16* Ab = As + (kt & 1) * 4096;
        const bf16* Bb = Bs + (kt & 1) * 4096;
        const int sw = (quad ^ (mrow & 3)) * 8;
        bf16x8 af[4], bfr[4];
#pragma unroll
        for (int i = 0; i < 4; ++i)
            af[i] = *(const bf16x8*)(Ab + (wm + i * 16 + mrow) * 32 + sw);
#pragma unroll
        for (int j = 0; j < 4; ++j)
            bfr[j] = *(const bf16x8*)(Bb + (wn + j * 16 + mrow) * 32 + sw);
#pragma unroll
        for (int i = 0; i < 4; ++i)
#pragma unroll
            for (int j = 0; j < 4; ++j)
                acc[i][j] = MFMA16(af[i], bfr[j], acc[i][j]);
    }

#pragma unroll
    for (int i = 0; i < 4; ++i) {
#pragma unroll
        for (int j = 0; j < 4; ++j) {
            const int col = n0 + wn + j * 16 + mrow;
#pragma unroll
            for (int r = 0; r < 4; ++r) {
                const int row = m0 + wm + i * 16 + quad * 4 + r;
                float v = acc[i][j][r];
                if (md == 4) {
                    // V^T in permuted tile layout
                    v += bias3[row];
                    const int h = row >> 6, d = row & 63;
                    const int b = col >> 11, s = col & (SS - 1);
                    const int bh = b * HH + h;
                    const int kt2 = s >> 6, ci = (s >> 4) & 3, ji = s & 7;
                    const int mfi = (d >> 5) & 1;
                    const int lanei = (d & 31) + ((s >> 3) & 1) * 32;
                    outvt[(size_t)bh * 131072 + kt2 * 4096 + mfi * 2048 +
                          ci * 512 + lanei * 8 + ji] = (bf16)v;
                } else {
                    const int m2 = col >> 10;
                    const int cl = col & 1023;
                    const int h = cl >> 6, d = cl & 63;
                    const int b = row >> 11, s = row & (SS - 1);
                    v += (m2 ? bias2[cl] : bias[cl]);
                    v *= adapt[(b * HH + h) * DD + d];
                    if (!m2) {
                        // q: 1/sqrt(64) * log2(e) folded (attn uses exp2)
                        v *= 0.18033688011113811f;
                        outqk[((b * HH + h) * SS + s) * DD + d] = (bf16)v;
                    } else {
                        // K in permuted tile layout
                        const int bh = b * HH + h;
                        const int kt2 = s >> 6, mfi = (s >> 5) & 1;
                        const int ci = d >> 4, ji = d & 7;
                        const int lanei = (s & 31) + ((d >> 3) & 1) * 32;
                        outqk[(size_t)MM * EE + (size_t)bh * 131072 + kt2 * 4096 +
                              mfi * 2048 + ci * 512 + lanei * 8 + ji] = (bf16)v;
                    }
                }
            }
        }
    }
}

// ---------------------------------------------------------------------------
// Kernel 3: final GEMM.
// ---------------------------------------------------------------------------
__global__ __launch_bounds__(256, 3) void gemm_o(
    const bf16* __restrict__ A, const bf16* __restrict__ Bt,
    const float* __restrict__ bias, float* __restrict__ outf) {
    __shared__ bf16 As[2 * 128 * 64];
    __shared__ bf16 Bs[2 * 64 * 64];

    const int t = threadIdx.x;
    const int w = t >> 6, lane = t & 63;
    const int mrow = lane & 15, quad = lane >> 4;
    const int m0 = blockIdx.x * 128, n0 = blockIdx.y * 64;

    f32x4 acc[2][4];
#pragma unroll
    for (int i = 0; i < 2; ++i)
#pragma unroll
        for (int j = 0; j < 4; ++j) acc[i][j] = zero4();

    const int grow = lane >> 3;
    const int gsw = ((lane & 7) ^ grow) * 8;
    const bf16* Ag = A + (size_t)(m0 + w * 32 + grow) * EE + gsw;
    const bf16* Bg = Bt + (size_t)(n0 + w * 16 + grow) * EE + gsw;
    bf16* Al = As + (w * 32) * 64;
    bf16* Bl = Bs + (w * 16) * 64;

#pragma unroll
    for (int i = 0; i < 4; ++i) gload16(Ag + i * 8 * EE, Al + i * 8 * 64);
#pragma unroll
    for (int i = 0; i < 2; ++i) gload16(Bg + i * 8 * EE, Bl + i * 8 * 64);

    for (int kt = 0; kt < 16; ++kt) {
        __syncthreads();
        if (kt < 15) {
            const int kn = (kt + 1) * 64;
            const int nb = (kt + 1) & 1;
#pragma unroll
            for (int i = 0; i < 4; ++i)
                gload16(Ag + i * 8 * EE + kn, Al + nb * 8192 + i * 8 * 64);
#pragma unroll
            for (int i = 0; i < 2; ++i)
                gload16(Bg + i * 8 * EE + kn, Bl + nb * 4096 + i * 8 * 64);
        }
        const bf16* Ab = As + (kt & 1) * 8192;
        const bf16* Bb = Bs + (kt & 1) * 4096;
#pragma unroll
        for (int ks = 0; ks < 2; ++ks) {
            const int cg = ks * 4 + quad;
            const int sw = (cg ^ (mrow & 7)) * 8;
            bf16x8 af[2], bfr[4];
#pragma unroll
            for (int mi = 0; mi < 2; ++mi)
                af[mi] = *(const bf16x8*)(Ab + (w * 32 + mi * 16 + mrow) * 64 + sw);
#pragma unroll
            for (int nj = 0; nj < 4; ++nj)
                bfr[nj] = *(const bf16x8*)(Bb + (nj * 16 + mrow) * 64 + sw);
#pragma unroll
            for (int mi = 0; mi < 2; ++mi)
#pragma unroll
                for (int nj = 0; nj < 4; ++nj)
                    acc[mi][nj] = MFMA16(af[mi], bfr[nj], acc[mi][nj]);
        }
    }

#pragma unroll
    for (int mi = 0; mi < 2; ++mi) {
#pragma unroll
        for (int nj = 0; nj < 4; ++nj) {
            const int col = n0 + nj * 16 + mrow;
#pragma unroll
            for (int r = 0; r < 4; ++r) {
                const int row = m0 + w * 32 + mi * 16 + quad * 4 + r;
                outf[row * EE + col] = acc[mi][nj][r] + bias[col];
            }
        }
    }
}

// ---------------------------------------------------------------------------
// Kernel 4: flash attention — R4: LDS-FREE main loop.
// R3 post-mortem: R1 (1 blk/CU) and R2 (2 blk/CU, 2x LDS traffic) timed
// IDENTICALLY -> not occupancy-, not LDS-BW-bound; the barrier-lockstepped
// per-score serial chain was the limit.  K/V are L2-resident (512KB/bh, 4
// bh/XCD via bid&31 swizzle), so staging is pure overhead (m169 precedent).
// Now: K/V read global->reg from gemm_qkv's permuted tile layout (fully
// coalesced 1KB wave loads).  V issued at iter start, used at iter end (QK+
// softmax covers L2 latency); K register-double-buffered one tile ahead
// (2-step unrolled loop, static indexing).  NO barriers in the main loop.
// lsum split into 4 chains; s_setprio around MFMA clusters (T5).
// Dead ends: split-K (nondeterminism), K-tile 32/128, forced 4 blk/CU.
// ---------------------------------------------------------------------------
__device__ __forceinline__ void attn_step(
    int kt, const bf16* kbase, const bf16* vbase,
    const bf16x8 (&qf)[4], bf16x8 (&KU)[8], bf16x8 (&KP)[8],
    f32x16 (&oacc)[2], float (&ls)[4], int h) {
    // V fragments for this tile: 8 coalesced 1KB loads, consumed at PV below
    bf16x8 vf[8];
#pragma unroll
    for (int mf = 0; mf < 2; ++mf)
#pragma unroll
        for (int c = 0; c < 4; ++c)
            vf[mf * 4 + c] = *(const bf16x8*)(vbase + kt * 4096 + mf * 2048 + c * 512);

    // ---- S^T = K·Q^T from registers ----
    f32x16 st[2];
#pragma unroll
    for (int mf = 0; mf < 2; ++mf)
#pragma unroll
        for (int i = 0; i < 16; ++i) st[mf][i] = 0.f;
    __builtin_amdgcn_s_setprio(1);
#pragma unroll
    for (int c = 0; c < 4; ++c)
#pragma unroll
        for (int mf = 0; mf < 2; ++mf)
            st[mf] = MFMA32(KU[mf * 4 + c], qf[c], st[mf]);
    __builtin_amdgcn_s_setprio(0);

    // ---- prefetch next K tile into the other register set ----
    const int ktp = kt + (kt < SS / 64 - 1 ? 1 : 0);
#pragma unroll
    for (int mf = 0; mf < 2; ++mf)
#pragma unroll
        for (int c = 0; c < 4; ++c)
            KP[mf * 4 + c] = *(const bf16x8*)(kbase + ktp * 4096 + mf * 2048 + c * 512);

    // ---- p = exp2(s') (q carries log2e), pack; 4 lsum chains ----
    u32 P32[2][8];
#pragma unroll
    for (int mf = 0; mf < 2; ++mf)
#pragma unroll
        for (int rp = 0; rp < 8; ++rp) {
            float pa = __builtin_amdgcn_exp2f(st[mf][2 * rp]);
            float pb = __builtin_amdgcn_exp2f(st[mf][2 * rp + 1]);
            ls[rp & 3] += pa + pb;
            P32[mf][rp] = pkbf(pa, pb);
        }

    // ---- PV from registers ----
#pragma unroll
    for (int c = 0; c < 4; ++c) {
        const int mfs = c >> 1;
        const int ro = (c & 1) * 4;
        union { u32 u[4]; bf16x8 v; } pb;
        {
            u32 vA0 = P32[mfs][ro + 0], vA1 = P32[mfs][ro + 1];
            u32 vB0 = P32[mfs][ro + 2], vB1 = P32[mfs][ro + 3];
            u32 prep0 = h ? vA0 : vB0;
            u32 prep1 = h ? vA1 : vB1;
            u32 sh0 = __shfl_xor(prep0, 32);
            u32 sh1 = __shfl_xor(prep1, 32);
            pb.u[0] = h ? sh0 : vA0;
            pb.u[1] = h ? sh1 : vA1;
            pb.u[2] = h ? vB0 : sh0;
            pb.u[3] = h ? vB1 : sh1;
        }
        __builtin_amdgcn_s_setprio(1);
#pragma unroll
        for (int mf = 0; mf < 2; ++mf)
            oacc[mf] = MFMA32(vf[mf * 4 + c], pb.v, oacc[mf]);
        __builtin_amdgcn_s_setprio(0);
    }
}

__global__ __launch_bounds__(256, 2) void attn_kernel(
    const bf16* __restrict__ q, const bf16* __restrict__ k,
    const bf16* __restrict__ vt, bf16* __restrict__ o0) {
    __shared__ bf16 lds[4 * 2112];  // epilogue transpose only (wave-private)

    const int t = threadIdx.x;
    const int w = t >> 6, lane = t & 63;
    const int q32 = lane & 31, h = lane >> 5;
    const int bh = blockIdx.x & 31;   // same-bh blocks share an XCD
    const int qb = blockIdx.x >> 5;   // 0..15 (128-row q tiles)
    const int qr0 = qb * 128 + w * 32;

    // Q B-frags (4 strided loads, once per kernel)
    bf16x8 qf[4];
#pragma unroll
    for (int c = 0; c < 4; ++c)
        qf[c] = *(const bf16x8*)(q + (size_t)(bh * SS + qr0 + q32) * DD + c * 16 + h * 8);

    // permuted-tile bases: fragment (kt,mf,c) at + kt*4096 + mf*2048 + c*512
    const bf16* kbase = k + (size_t)bh * 131072 + lane * 8;
    const bf16* vbase = vt + (size_t)bh * 131072 + lane * 8;

    f32x16 oacc[2];
#pragma unroll
    for (int mf = 0; mf < 2; ++mf)
#pragma unroll
        for (int i = 0; i < 16; ++i) oacc[mf][i] = 0.f;
    float ls[4] = {0.f, 0.f, 0.f, 0.f};

    // prologue: K tile 0 into set A
    bf16x8 Ka[8], Kb[8];
#pragma unroll
    for (int mf = 0; mf < 2; ++mf)
#pragma unroll
        for (int c = 0; c < 4; ++c)
            Ka[mf * 4 + c] = *(const bf16x8*)(kbase + mf * 2048 + c * 512);

    for (int kt2 = 0; kt2 < SS / 128; ++kt2) {
        attn_step(2 * kt2,     kbase, vbase, qf, Ka, Kb, oacc, ls, h);
        attn_step(2 * kt2 + 1, kbase, vbase, qf, Kb, Ka, oacc, ls, h);
    }

    float lsum = (ls[0] + ls[1]) + (ls[2] + ls[3]);
    lsum += __shfl_xor(lsum, 32);
    const float inv = 1.f / lsum;

    // ---- epilogue: O^T regs (normalized) -> per-wave LDS transpose -> store
    bf16* ob = lds + w * 2112;  // 32 rows x stride 66, wave-private
#pragma unroll
    for (int mf = 0; mf < 2; ++mf)
#pragma unroll
        for (int rp = 0; rp < 8; ++rp) {
            const int d = 32 * mf + 2 * (rp & 1) + 8 * (rp >> 1) + 4 * h;
            *(u32*)(ob + q32 * 66 + d) =
                pkbf(oacc[mf][2 * rp] * inv, oacc[mf][2 * rp + 1] * inv);
        }
    __syncthreads();  // ordering for the LDS readback (cheap, once)

    const int b = bh >> 4, head = bh & 15;
    const int half = lane & 1;
    const int r = lane >> 1;
#pragma unroll
    for (int i = 0; i < 4; ++i) {
        bf16x8 val = *(const bf16x8*)(ob + r * 66 + half * 32 + i * 8);
        *(bf16x8*)(o0 + (size_t)(b * SS + qr0 + r) * EE + head * DD +
                   half * 32 + i * 8) = val;
    }
}

// ---------------------------------------------------------------------------
// Single scratch layout, everything in d_ws (40 MiB).  d_out written exactly
// once, by gemm_o.
// ---------------------------------------------------------------------------
extern "C" void kernel_launch(void* const* d_in, const int* in_sizes, int n_in,
                              void* d_out, int out_size, void* d_ws, size_t ws_size,
                              hipStream_t stream) {
    const float* query = (const float*)d_in[0];
    const float* xi    = (const float*)d_in[1];
    const float* Wq = (const float*)d_in[2];  const float* bq = (const float*)d_in[3];
    const float* Wk = (const float*)d_in[4];  const float* bk = (const float*)d_in[5];
    const float* Wv = (const float*)d_in[6];  const float* bv = (const float*)d_in[7];
    const float* Wo = (const float*)d_in[8];  const float* bo = (const float*)d_in[9];
    const float* ew1 = (const float*)d_in[10]; const float* eb1 = (const float*)d_in[11];
    const float* lng = (const float*)d_in[12]; const float* lnb = (const float*)d_in[13];
    const float* ew2 = (const float*)d_in[14]; const float* eb2 = (const float*)d_in[15];
    const float* gate = (const float*)d_in[16];
    float* out = (float*)d_out;

    char* ws = (char*)d_ws;
    const size_t SZ = (size_t)MM * EE * sizeof(bf16);   // 8 MB
    const size_t WSZ = (size_t)EE * EE * sizeof(bf16);  // 2 MB per transposed weight

    bf16* queryc = (bf16*)(ws);            // dead after gemm_qkv
    bf16* p0     = (bf16*)(ws);            // attn output overlays queryc
    bf16* qws    = (bf16*)(ws + SZ);
    bf16* kws    = (bf16*)(ws + 2 * SZ);
    bf16* vtws   = (bf16*)(ws + 3 * SZ);
    bf16* wqT    = (bf16*)(ws + 4 * SZ);
    bf16* wkT    = (bf16*)(ws + 4 * SZ + WSZ);
    bf16* wvT    = (bf16*)(ws + 4 * SZ + 2 * WSZ);
    bf16* woT    = (bf16*)(ws + 4 * SZ + 3 * WSZ);
    float* adaptws = (float*)(ws + 4 * SZ + 4 * WSZ);

    prep_kernel<<<3074, 256, 0, stream>>>(query, queryc, Wq, Wk, Wv, Wo,
                                          wqT, wkT, wvT, woT,
                                          xi, ew1, eb1, lng, lnb, ew2, eb2, gate,
                                          adaptws);

    // combined QK (512) + V^T (256) = 768 blocks = 3/CU
    gemm_qkv<<<768, 256, 0, stream>>>(queryc, wqT, wvT, bq, bk, bv, adaptws,
                                      qws, vtws);

    // 32 bh x 16 q-tiles = 512 blocks of 256 threads (full K-range per block)
    attn_kernel<<<512, 256, 0, stream>>>(qws, kws, vtws, p0);

    gemm_o<<<dim3(MM / 128, EE / 64), 256, 0, stream>>>(p0, woT, bo, out);
}

// Round 5
// 205.428 us; speedup vs baseline: 1.0626x; 1.0502x over previous
//
#include <hip/hip_runtime.h>

typedef __bf16 bf16;
typedef __attribute__((ext_vector_type(8))) __bf16 bf16x8;
typedef __attribute__((ext_vector_type(4))) float f32x4;
typedef __attribute__((ext_vector_type(16))) float f32x16;
typedef unsigned int u32;

#define MFMA16(a, b, c) __builtin_amdgcn_mfma_f32_16x16x32_bf16((a), (b), (c), 0, 0, 0)
#define MFMA32(a, b, c) __builtin_amdgcn_mfma_f32_32x32x16_bf16((a), (b), (c), 0, 0, 0)

// Problem constants
#define BB 2
#define SS 2048
#define EE 1024
#define HH 16
#define DD 64
#define MM (BB * SS)  // 4096

__device__ inline f32x4 zero4() {
    f32x4 z; z.x = 0.f; z.y = 0.f; z.z = 0.f; z.w = 0.f; return z;
}

// async global->LDS DMA, 16B per lane.  LDS dest = wave-uniform base + lane*16.
__device__ __forceinline__ void gload16(const bf16* g, bf16* l) {
    __builtin_amdgcn_global_load_lds(
        (const __attribute__((address_space(1))) u32*)(const void*)g,
        (__attribute__((address_space(3))) u32*)(void*)l,
        16, 0, 0);
}

__device__ __forceinline__ u32 pkbf(float a, float b) {
    union { __bf16 h; unsigned short s; } ua, ub;
    ua.h = (__bf16)a; ub.h = (__bf16)b;
    return (u32)ua.s | ((u32)ub.s << 16);
}

// ---------------------------------------------------------------------------
// Kernel 1: fused prep.
// ---------------------------------------------------------------------------
__global__ __launch_bounds__(256) void prep_kernel(
    const float* __restrict__ query, bf16* __restrict__ qc,
    const float* __restrict__ s0, const float* __restrict__ s1,
    const float* __restrict__ s2, const float* __restrict__ s3,
    bf16* __restrict__ d0, bf16* __restrict__ d1,
    bf16* __restrict__ d2, bf16* __restrict__ d3,
    const float* __restrict__ xi, const float* __restrict__ w1,
    const float* __restrict__ b1, const float* __restrict__ lng,
    const float* __restrict__ lnb, const float* __restrict__ w2,
    const float* __restrict__ b2, const float* __restrict__ gate,
    float* __restrict__ adapt) {
    __shared__ bf16 tile[64 * 72];
    const int bid = blockIdx.x;
    const int t = threadIdx.x;

    if (bid < 2048) {
        const int i = (bid * 256 + t) * 8;
        float4 a = *(const float4*)(query + i);
        float4 b = *(const float4*)(query + i + 4);
        bf16 tmp[8];
        tmp[0] = (bf16)a.x; tmp[1] = (bf16)a.y; tmp[2] = (bf16)a.z; tmp[3] = (bf16)a.w;
        tmp[4] = (bf16)b.x; tmp[5] = (bf16)b.y; tmp[6] = (bf16)b.z; tmp[7] = (bf16)b.w;
        *(uint4*)(qc + i) = *(uint4*)tmp;
    } else if (bid < 3072) {
        const int m = (bid - 2048) >> 8;
        const int idx0 = (bid - 2048) & 255;
        const float* W = (m == 0) ? s0 : (m == 1) ? s1 : (m == 2) ? s2 : s3;
        bf16* Wt = (m == 0) ? d0 : (m == 1) ? d1 : (m == 2) ? d2 : d3;
        const int k0 = (idx0 >> 4) * 64, n0 = (idx0 & 15) * 64;
#pragma unroll
        for (int i = 0; i < 2; ++i) {
            int idx = i * 256 + t;
            int r = idx >> 3, c = (idx & 7) * 8;
            float4 a = *(const float4*)(W + (k0 + r) * EE + n0 + c);
            float4 b = *(const float4*)(W + (k0 + r) * EE + n0 + c + 4);
            bf16 tmp[8];
            tmp[0] = (bf16)a.x; tmp[1] = (bf16)a.y; tmp[2] = (bf16)a.z; tmp[3] = (bf16)a.w;
            tmp[4] = (bf16)b.x; tmp[5] = (bf16)b.y; tmp[6] = (bf16)b.z; tmp[7] = (bf16)b.w;
            *(uint4*)(tile + r * 72 + c) = *(uint4*)tmp;
        }
        __syncthreads();
#pragma unroll
        for (int i = 0; i < 2; ++i) {
            int idx = i * 256 + t;
            int n = idx >> 3, kc = (idx & 7) * 8;
            bf16 tmp[8];
#pragma unroll
            for (int j = 0; j < 8; ++j) tmp[j] = tile[(kc + j) * 72 + n];
            *(uint4*)(Wt + (n0 + n) * EE + k0 + kc) = *(uint4*)tmp;
        }
    } else {
        const int b = bid - 3072;
        float* xs = (float*)tile;
        if (t < 64) {
            const float xiv = xi[b];
            float xv = 0.f;
            if (t < 32) xv = xiv * w1[t] + b1[t];
            float sm = xv;
            for (int off = 1; off < 32; off <<= 1) sm += __shfl_xor(sm, off);
            const float mu = sm * (1.f / 32.f);
            float dv = (t < 32) ? (xv - mu) : 0.f;
            float s2 = dv * dv;
            for (int off = 1; off < 32; off <<= 1) s2 += __shfl_xor(s2, off);
            const float var = s2 * (1.f / 32.f);
            if (t < 32) {
                float xn = (xv - mu) * rsqrtf(var + 1e-5f) * lng[t] + lnb[t];
                float ge = 0.5f * xn * (1.f + erff(xn * 0.70710678118654752f));
                xs[t] = ge;
            }
        }
        __syncthreads();
        if (t < 64) {
            float acc = b2[t];
            for (int j = 0; j < 32; ++j) acc += xs[j] * w2[j * DD + t];
            for (int h = 0; h < HH; ++h) {
                float sg = 1.f / (1.f + __expf(-gate[h]));
                adapt[(b * HH + h) * DD + t] = 1.f + sg * acc;
            }
        }
    }
}

// ---------------------------------------------------------------------------
// Kernel 2: QKV GEMM — 128x128 tile, BK=32, dbuf DMA, one barrier/iter.
// q-scale folds 0.125*log2(e) so attention uses bare v_exp_f32 (exp2).
// K and V^T outputs in PERMUTED TILE LAYOUT (R4):
//   idx = bh*131072 + kt*4096 + mf*2048 + c*512 + lane*8 + j
//   K:  s = kt*64 + mf*32 + (lane&31), d = c*16 + (lane>>5)*8 + j
//   V^T: d = mf*32 + (lane&31),        s = kt*64 + c*16 + (lane>>5)*8 + j
// R5: epilogue v2 — the old epilogue issued 64 scalar scattered stores per
// thread (12.6M VMEM instrs kernel-wide ~= 82us of pure store issue; counters
// showed MfmaUtil 16 / VALUBusy 15 / hbm 16% — issue-bound, nothing busy).
// Now: scaled bf16 results -> XOR-swizzled LDS tile (staging LDS is dead
// after the K-loop) -> 8 x dwordx4 stores per thread (8x fewer VMEM instrs,
// same bytes).  bias/adapt hoisted to 4 per-column FMA factors.
// ---------------------------------------------------------------------------
__global__ __launch_bounds__(256, 3) void gemm_qkv(
    const bf16* __restrict__ Aq, const bf16* __restrict__ Bqk,
    const bf16* __restrict__ Av,
    const float* __restrict__ bias, const float* __restrict__ bias2,
    const float* __restrict__ bias3, const float* __restrict__ adapt,
    bf16* __restrict__ outqk, bf16* __restrict__ outvt) {
    __shared__ bf16 sh[16384];  // main loop: As=sh[0:8192), Bs=sh[8192:16384)
                                // epilogue: 128x128 bf16 tile (32KB), swizzled
    bf16* As = sh;
    bf16* Bs = sh + 8192;

    const int t = threadIdx.x;
    const int w = t >> 6, lane = t & 63;
    const int mrow = lane & 15, quad = lane >> 4;
    const int wm = (w & 1) * 64, wn = (w >> 1) * 64;

    int md, bx, by;
    const bf16 *Ap, *Bp;
    int bid = blockIdx.x;
    if (bid < 512) { md = 5; bx = bid & 31; by = bid >> 5; Ap = Aq; Bp = Bqk; }
    else { md = 4; bid -= 512; bx = bid & 7; by = bid >> 3; Ap = Av; Bp = Aq; }
    const int m0 = bx * 128, n0 = by * 128;
    const int m2 = (md == 5) ? (by >> 3) : 0;  // 0=Q, 1=K (block-uniform)

    f32x4 acc[4][4];
#pragma unroll
    for (int i = 0; i < 4; ++i)
#pragma unroll
        for (int j = 0; j < 4; ++j) acc[i][j] = zero4();

    const int dr = lane >> 2;
    const int dcg = ((lane & 3) ^ (dr & 3)) * 8;
    const bf16* Ag = Ap + (size_t)(m0 + w * 16 + dr) * EE + dcg;
    const bf16* Bg = Bp + (size_t)(n0 + w * 16 + dr) * EE + dcg;
    bf16* Al = As + (w * 16) * 32;
    bf16* Bl = Bs + (w * 16) * 32;

    gload16(Ag, Al);
    gload16(Ag + 64 * EE, Al + 64 * 32);
    gload16(Bg, Bl);
    gload16(Bg + 64 * EE, Bl + 64 * 32);

    for (int kt = 0; kt < 32; ++kt) {
        __syncthreads();
        if (kt < 31) {
            const int kn = (kt + 1) * 32;
            const int nb = (kt + 1) & 1;
            gload16(Ag + kn, Al + nb * 4096);
            gload16(Ag + 64 * EE + kn, Al + nb * 4096 + 64 * 32);
            gload16(Bg + kn, Bl + nb * 4096);
            gload16(Bg + 64 * EE + kn, Bl + nb * 4096 + 64 * 32);
        }
        const bf16* Ab = As + (kt & 1) * 4096;
        const bf16* Bb = Bs + (kt & 1) * 4096;
        const int sw = (quad ^ (mrow & 3)) * 8;
        bf16x8 af[4], bfr[4];
#pragma unroll
        for (int i = 0; i < 4; ++i)
            af[i] = *(const bf16x8*)(Ab + (wm + i * 16 + mrow) * 32 + sw);
#pragma unroll
        for (int j = 0; j < 4; ++j)
            bfr[j] = *(const bf16x8*)(Bb + (wn + j * 16 + mrow) * 32 + sw);
#pragma unroll
        for (int i = 0; i < 4; ++i)
#pragma unroll
            for (int j = 0; j < 4; ++j)
                acc[i][j] = MFMA16(af[i], bfr[j], acc[i][j]);
    }

    // ---- epilogue v2: scale -> swizzled LDS -> vectorized stores ----
    __syncthreads();  // staging LDS now dead; safe to overwrite

    if (md == 5) {
        const int bq_ = m0 >> 11;
        float cmul[4], cadd[4];
#pragma unroll
        for (int j = 0; j < 4; ++j) {
            const int cl = (n0 & 1023) + wn + j * 16 + mrow;
            const int hh = cl >> 6, dd2 = cl & 63;
            const float ad = adapt[(bq_ * HH + hh) * DD + dd2];
            const float sc = m2 ? 1.f : 0.18033688011113811f;
            cmul[j] = ad * sc;
            cadd[j] = (m2 ? bias2[cl] : bias[cl]) * ad * sc;
        }
#pragma unroll
        for (int i = 0; i < 4; ++i)
#pragma unroll
            for (int j = 0; j < 4; ++j) {
                const int lcol = wn + j * 16 + mrow;
#pragma unroll
                for (int r = 0; r < 4; ++r) {
                    const int lrow = wm + i * 16 + quad * 4 + r;
                    const float v = acc[i][j][r] * cmul[j] + cadd[j];
                    *(bf16*)((char*)sh + lrow * 256 +
                             ((lcol * 2) ^ ((lrow & 15) << 4))) = (bf16)v;
                }
            }
    } else {
        float radd[16];
#pragma unroll
        for (int i = 0; i < 4; ++i)
#pragma unroll
            for (int r = 0; r < 4; ++r)
                radd[i * 4 + r] = bias3[m0 + wm + i * 16 + quad * 4 + r];
#pragma unroll
        for (int i = 0; i < 4; ++i)
#pragma unroll
            for (int j = 0; j < 4; ++j) {
                const int lcol = wn + j * 16 + mrow;
#pragma unroll
                for (int r = 0; r < 4; ++r) {
                    const int lrow = wm + i * 16 + quad * 4 + r;
                    const float v = acc[i][j][r] + radd[i * 4 + r];
                    *(bf16*)((char*)sh + lrow * 256 +
                             ((lcol * 2) ^ ((lrow & 15) << 4))) = (bf16)v;
                }
            }
    }
    __syncthreads();

#pragma unroll
    for (int p = 0; p < 8; ++p) {
        const int lrow = p * 16 + (t >> 4);
        const int lcol0 = (t & 15) * 8;
        bf16x8 val = *(const bf16x8*)((const char*)sh + lrow * 256 +
                                      ((lcol0 * 2) ^ ((lrow & 15) << 4)));
        if (md == 5) {
            const int bq_ = m0 >> 11;
            const int s_ = (m0 + lrow) & (SS - 1);
            const int cl = (n0 & 1023) + lcol0;
            const int hh = cl >> 6, d0 = cl & 63;
            if (!m2) {
                *(bf16x8*)(outqk + ((size_t)(bq_ * HH + hh) * SS + s_) * DD + d0) = val;
            } else {
                const size_t base = (size_t)MM * EE + (size_t)(bq_ * HH + hh) * 131072;
                const int a2 = (s_ >> 6) * 4096 + ((s_ >> 5) & 1) * 2048 +
                               (d0 >> 4) * 512 +
                               ((s_ & 31) + ((d0 >> 3) & 1) * 32) * 8;
                *(bf16x8*)(outqk + base + a2) = val;
            }
        } else {
            const int rowv = m0 + lrow;
            const int hv = rowv >> 6, dv = rowv & 63;
            const int colv = n0 + lcol0;
            const int bv_ = colv >> 11, sv = colv & (SS - 1);
            const size_t base = (size_t)(bv_ * HH + hv) * 131072;
            const int a2 = (sv >> 6) * 4096 + (dv >> 5) * 2048 +
                           ((sv >> 4) & 3) * 512 +
                           ((dv & 31) + ((sv >> 3) & 1) * 32) * 8;
            *(bf16x8*)(outvt + base + a2) = val;
        }
    }
}

// ---------------------------------------------------------------------------
// Kernel 3: final GEMM.  R5: same epilogue-v2 treatment — 32 scalar f32
// stores/thread -> f32 tile in swizzled LDS -> 8 x float4 stores/thread.
// ---------------------------------------------------------------------------
__global__ __launch_bounds__(256, 3) void gemm_o(
    const bf16* __restrict__ A, const bf16* __restrict__ Bt,
    const float* __restrict__ bias, float* __restrict__ outf) {
    __shared__ bf16 As[2 * 128 * 64];  // 32KB; epilogue reuses as 128x64 f32
    __shared__ bf16 Bs[2 * 64 * 64];

    const int t = threadIdx.x;
    const int w = t >> 6, lane = t & 63;
    const int mrow = lane & 15, quad = lane >> 4;
    const int m0 = blockIdx.x * 128, n0 = blockIdx.y * 64;

    f32x4 acc[2][4];
#pragma unroll
    for (int i = 0; i < 2; ++i)
#pragma unroll
        for (int j = 0; j < 4; ++j) acc[i][j] = zero4();

    const int grow = lane >> 3;
    const int gsw = ((lane & 7) ^ grow) * 8;
    const bf16* Ag = A + (size_t)(m0 + w * 32 + grow) * EE + gsw;
    const bf16* Bg = Bt + (size_t)(n0 + w * 16 + grow) * EE + gsw;
    bf16* Al = As + (w * 32) * 64;
    bf16* Bl = Bs + (w * 16) * 64;

#pragma unroll
    for (int i = 0; i < 4; ++i) gload16(Ag + i * 8 * EE, Al + i * 8 * 64);
#pragma unroll
    for (int i = 0; i < 2; ++i) gload16(Bg + i * 8 * EE, Bl + i * 8 * 64);

    for (int kt = 0; kt < 16; ++kt) {
        __syncthreads();
        if (kt < 15) {
            const int kn = (kt + 1) * 64;
            const int nb = (kt + 1) & 1;
#pragma unroll
            for (int i = 0; i < 4; ++i)
                gload16(Ag + i * 8 * EE + kn, Al + nb * 8192 + i * 8 * 64);
#pragma unroll
            for (int i = 0; i < 2; ++i)
                gload16(Bg + i * 8 * EE + kn, Bl + nb * 4096 + i * 8 * 64);
        }
        const bf16* Ab = As + (kt & 1) * 8192;
        const bf16* Bb = Bs + (kt & 1) * 4096;
#pragma unroll
        for (int ks = 0; ks < 2; ++ks) {
            const int cg = ks * 4 + quad;
            const int sw = (cg ^ (mrow & 7)) * 8;
            bf16x8 af[2], bfr[4];
#pragma unroll
            for (int mi = 0; mi < 2; ++mi)
                af[mi] = *(const bf16x8*)(Ab + (w * 32 + mi * 16 + mrow) * 64 + sw);
#pragma unroll
            for (int nj = 0; nj < 4; ++nj)
                bfr[nj] = *(const bf16x8*)(Bb + (nj * 16 + mrow) * 64 + sw);
#pragma unroll
            for (int mi = 0; mi < 2; ++mi)
#pragma unroll
                for (int nj = 0; nj < 4; ++nj)
                    acc[mi][nj] = MFMA16(af[mi], bfr[nj], acc[mi][nj]);
        }
    }

    // ---- epilogue v2 ----
    __syncthreads();  // staging LDS dead
    char* fs = (char*)As;  // 128 rows x 256B (64 f32), swizzled
    float cadd[4];
#pragma unroll
    for (int nj = 0; nj < 4; ++nj) cadd[nj] = bias[n0 + nj * 16 + mrow];
#pragma unroll
    for (int mi = 0; mi < 2; ++mi)
#pragma unroll
        for (int nj = 0; nj < 4; ++nj) {
            const int lcol = nj * 16 + mrow;
#pragma unroll
            for (int r = 0; r < 4; ++r) {
                const int lrow = w * 32 + mi * 16 + quad * 4 + r;
                *(float*)(fs + lrow * 256 + ((lcol * 4) ^ ((lrow & 15) << 4))) =
                    acc[mi][nj][r] + cadd[nj];
            }
        }
    __syncthreads();

#pragma unroll
    for (int p = 0; p < 8; ++p) {
        const int lrow = p * 16 + (t >> 4);
        const int lcol0 = (t & 15) * 4;
        float4 val = *(const float4*)(fs + lrow * 256 +
                                      ((lcol0 * 4) ^ ((lrow & 15) << 4)));
        *(float4*)(outf + (size_t)(m0 + lrow) * EE + n0 + lcol0) = val;
    }
}

// ---------------------------------------------------------------------------
// Kernel 4: flash attention — LDS-free main loop (R4, verified).
// K/V read global->reg from the permuted tile layout (coalesced 1KB wave
// loads, L2-served via bid&31 XCD affinity).  V issued at iter start /
// consumed at iter end; K register-double-buffered one tile ahead; NO
// barriers in the main loop.  lsum in 4 chains; setprio around MFMA.
// Dead ends: split-K (nondeterminism), K-tile 32/128, LDS staging (R1-R3:
// barrier-lockstep invariant ~61us regardless of occupancy).
// ---------------------------------------------------------------------------
__device__ __forceinline__ void attn_step(
    int kt, const bf16* kbase, const bf16* vbase,
    const bf16x8 (&qf)[4], bf16x8 (&KU)[8], bf16x8 (&KP)[8],
    f32x16 (&oacc)[2], float (&ls)[4], int h) {
    bf16x8 vf[8];
#pragma unroll
    for (int mf = 0; mf < 2; ++mf)
#pragma unroll
        for (int c = 0; c < 4; ++c)
            vf[mf * 4 + c] = *(const bf16x8*)(vbase + kt * 4096 + mf * 2048 + c * 512);

    f32x16 st[2];
#pragma unroll
    for (int mf = 0; mf < 2; ++mf)
#pragma unroll
        for (int i = 0; i < 16; ++i) st[mf][i] = 0.f;
    __builtin_amdgcn_s_setprio(1);
#pragma unroll
    for (int c = 0; c < 4; ++c)
#pragma unroll
        for (int mf = 0; mf < 2; ++mf)
            st[mf] = MFMA32(KU[mf * 4 + c], qf[c], st[mf]);
    __builtin_amdgcn_s_setprio(0);

    const int ktp = kt + (kt < SS / 64 - 1 ? 1 : 0);
#pragma unroll
    for (int mf = 0; mf < 2; ++mf)
#pragma unroll
        for (int c = 0; c < 4; ++c)
            KP[mf * 4 + c] = *(const bf16x8*)(kbase + ktp * 4096 + mf * 2048 + c * 512);

    u32 P32[2][8];
#pragma unroll
    for (int mf = 0; mf < 2; ++mf)
#pragma unroll
        for (int rp = 0; rp < 8; ++rp) {
            float pa = __builtin_amdgcn_exp2f(st[mf][2 * rp]);
            float pb = __builtin_amdgcn_exp2f(st[mf][2 * rp + 1]);
            ls[rp & 3] += pa + pb;
            P32[mf][rp] = pkbf(pa, pb);
        }

#pragma unroll
    for (int c = 0; c < 4; ++c) {
        const int mfs = c >> 1;
        const int ro = (c & 1) * 4;
        union { u32 u[4]; bf16x8 v; } pb;
        {
            u32 vA0 = P32[mfs][ro + 0], vA1 = P32[mfs][ro + 1];
            u32 vB0 = P32[mfs][ro + 2], vB1 = P32[mfs][ro + 3];
            u32 prep0 = h ? vA0 : vB0;
            u32 prep1 = h ? vA1 : vB1;
            u32 sh0 = __shfl_xor(prep0, 32);
            u32 sh1 = __shfl_xor(prep1, 32);
            pb.u[0] = h ? sh0 : vA0;
            pb.u[1] = h ? sh1 : vA1;
            pb.u[2] = h ? vB0 : sh0;
            pb.u[3] = h ? vB1 : sh1;
        }
        __builtin_amdgcn_s_setprio(1);
#pragma unroll
        for (int mf = 0; mf < 2; ++mf)
            oacc[mf] = MFMA32(vf[mf * 4 + c], pb.v, oacc[mf]);
        __builtin_amdgcn_s_setprio(0);
    }
}

__global__ __launch_bounds__(256, 2) void attn_kernel(
    const bf16* __restrict__ q, const bf16* __restrict__ k,
    const bf16* __restrict__ vt, bf16* __restrict__ o0) {
    __shared__ bf16 lds[4 * 2112];  // epilogue transpose only (wave-private)

    const int t = threadIdx.x;
    const int w = t >> 6, lane = t & 63;
    const int q32 = lane & 31, h = lane >> 5;
    const int bh = blockIdx.x & 31;   // same-bh blocks share an XCD
    const int qb = blockIdx.x >> 5;   // 0..15 (128-row q tiles)
    const int qr0 = qb * 128 + w * 32;

    bf16x8 qf[4];
#pragma unroll
    for (int c = 0; c < 4; ++c)
        qf[c] = *(const bf16x8*)(q + (size_t)(bh * SS + qr0 + q32) * DD + c * 16 + h * 8);

    const bf16* kbase = k + (size_t)bh * 131072 + lane * 8;
    const bf16* vbase = vt + (size_t)bh * 131072 + lane * 8;

    f32x16 oacc[2];
#pragma unroll
    for (int mf = 0; mf < 2; ++mf)
#pragma unroll
        for (int i = 0; i < 16; ++i) oacc[mf][i] = 0.f;
    float ls[4] = {0.f, 0.f, 0.f, 0.f};

    bf16x8 Ka[8], Kb[8];
#pragma unroll
    for (int mf = 0; mf < 2; ++mf)
#pragma unroll
        for (int c = 0; c < 4; ++c)
            Ka[mf * 4 + c] = *(const bf16x8*)(kbase + mf * 2048 + c * 512);

    for (int kt2 = 0; kt2 < SS / 128; ++kt2) {
        attn_step(2 * kt2,     kbase, vbase, qf, Ka, Kb, oacc, ls, h);
        attn_step(2 * kt2 + 1, kbase, vbase, qf, Kb, Ka, oacc, ls, h);
    }

    float lsum = (ls[0] + ls[1]) + (ls[2] + ls[3]);
    lsum += __shfl_xor(lsum, 32);
    const float inv = 1.f / lsum;

    bf16* ob = lds + w * 2112;  // 32 rows x stride 66, wave-private
#pragma unroll
    for (int mf = 0; mf < 2; ++mf)
#pragma unroll
        for (int rp = 0; rp < 8; ++rp) {
            const int d = 32 * mf + 2 * (rp & 1) + 8 * (rp >> 1) + 4 * h;
            *(u32*)(ob + q32 * 66 + d) =
                pkbf(oacc[mf][2 * rp] * inv, oacc[mf][2 * rp + 1] * inv);
        }
    __syncthreads();

    const int b = bh >> 4, head = bh & 15;
    const int half = lane & 1;
    const int r = lane >> 1;
#pragma unroll
    for (int i = 0; i < 4; ++i) {
        bf16x8 val = *(const bf16x8*)(ob + r * 66 + half * 32 + i * 8);
        *(bf16x8*)(o0 + (size_t)(b * SS + qr0 + r) * EE + head * DD +
                   half * 32 + i * 8) = val;
    }
}

// ---------------------------------------------------------------------------
// Single scratch layout, everything in d_ws (40 MiB).  d_out written exactly
// once, by gemm_o.
// ---------------------------------------------------------------------------
extern "C" void kernel_launch(void* const* d_in, const int* in_sizes, int n_in,
                              void* d_out, int out_size, void* d_ws, size_t ws_size,
                              hipStream_t stream) {
    const float* query = (const float*)d_in[0];
    const float* xi    = (const float*)d_in[1];
    const float* Wq = (const float*)d_in[2];  const float* bq = (const float*)d_in[3];
    const float* Wk = (const float*)d_in[4];  const float* bk = (const float*)d_in[5];
    const float* Wv = (const float*)d_in[6];  const float* bv = (const float*)d_in[7];
    const float* Wo = (const float*)d_in[8];  const float* bo = (const float*)d_in[9];
    const float* ew1 = (const float*)d_in[10]; const float* eb1 = (const float*)d_in[11];
    const float* lng = (const float*)d_in[12]; const float* lnb = (const float*)d_in[13];
    const float* ew2 = (const float*)d_in[14]; const float* eb2 = (const float*)d_in[15];
    const float* gate = (const float*)d_in[16];
    float* out = (float*)d_out;

    char* ws = (char*)d_ws;
    const size_t SZ = (size_t)MM * EE * sizeof(bf16);   // 8 MB
    const size_t WSZ = (size_t)EE * EE * sizeof(bf16);  // 2 MB per transposed weight

    bf16* queryc = (bf16*)(ws);            // dead after gemm_qkv
    bf16* p0     = (bf16*)(ws);            // attn output overlays queryc
    bf16* qws    = (bf16*)(ws + SZ);
    bf16* kws    = (bf16*)(ws + 2 * SZ);
    bf16* vtws   = (bf16*)(ws + 3 * SZ);
    bf16* wqT    = (bf16*)(ws + 4 * SZ);
    bf16* wkT    = (bf16*)(ws + 4 * SZ + WSZ);
    bf16* wvT    = (bf16*)(ws + 4 * SZ + 2 * WSZ);
    bf16* woT    = (bf16*)(ws + 4 * SZ + 3 * WSZ);
    float* adaptws = (float*)(ws + 4 * SZ + 4 * WSZ);

    prep_kernel<<<3074, 256, 0, stream>>>(query, queryc, Wq, Wk, Wv, Wo,
                                          wqT, wkT, wvT, woT,
                                          xi, ew1, eb1, lng, lnb, ew2, eb2, gate,
                                          adaptws);

    // combined QK (512) + V^T (256) = 768 blocks = 3/CU
    gemm_qkv<<<768, 256, 0, stream>>>(queryc, wqT, wvT, bq, bk, bv, adaptws,
                                      qws, vtws);

    // 32 bh x 16 q-tiles = 512 blocks of 256 threads (full K-range per block)
    attn_kernel<<<512, 256, 0, stream>>>(qws, kws, vtws, p0);

    gemm_o<<<dim3(MM / 128, EE / 64), 256, 0, stream>>>(p0, woT, bo, out);
}